// Round 6
// baseline (562.890 us; speedup 1.0000x reference)
//
#include <hip/hip_runtime.h>

typedef __attribute__((ext_vector_type(8))) short short8;
typedef __attribute__((ext_vector_type(4))) short short4v;
typedef __attribute__((ext_vector_type(4))) float f32x4;

#define BATCH  4
#define SLEN   2048
#define DMODEL 2048
#define NKV    8
#define GRP    4
#define DH     64
#define QKV    1536
#define KVDIM  512
#define MROWS  (BATCH * SLEN)   // 8192

// ---- bf16 helpers (RNE) ----------------------------------------------------
__device__ __forceinline__ unsigned short f2bf(float f) {
    unsigned u = __float_as_uint(f);
    u += 0x7FFFu + ((u >> 16) & 1u);
    return (unsigned short)(u >> 16);
}
__device__ __forceinline__ float bf2f(unsigned short h) {
    return __uint_as_float(((unsigned)h) << 16);
}

// ---- async global->LDS, 16B per lane ---------------------------------------
__device__ __forceinline__ void gl16(const void* g, void* l) {
    __builtin_amdgcn_global_load_lds(
        (const __attribute__((address_space(1))) void*)g,
        (__attribute__((address_space(3))) void*)l, 16, 0, 0);
}

union U64S4 { unsigned long long u; short4v s; };

// ---------------------------------------------------------------------------
// Kernel 1: pack weights into Wcat[d_model][1536] (fp32).
// ---------------------------------------------------------------------------
__global__ __launch_bounds__(256) void k_pack(const float* __restrict__ wq,
                                              const float* __restrict__ wk,
                                              const float* __restrict__ wv,
                                              float* __restrict__ wcat) {
    int i = blockIdx.x * 256 + threadIdx.x;
    if (i >= DMODEL * QKV) return;
    int d = i / QKV, c = i - d * QKV;
    int mat = c >> 9, rem = c & 511;
    int n = rem >> 6, h = rem & 63;
    float val;
    if (mat == 0) {
        val = 0.0f;
#pragma unroll
        for (int g = 0; g < GRP; ++g)
            val += wq[((size_t)(n * GRP + g) * DMODEL + d) * DH + h];
    } else if (mat == 1) {
        val = wk[((size_t)n * DMODEL + d) * DH + h];
    } else {
        val = wv[((size_t)n * DMODEL + d) * DH + h];
    }
    wcat[(size_t)d * QKV + c] = val;
}

// ---------------------------------------------------------------------------
// Kernel 2: transpose + split-convert. in fp32 [R][C] -> hi/lo ushort [C][R].
// ---------------------------------------------------------------------------
__global__ __launch_bounds__(256) void k_transconv(const float* __restrict__ in,
                                                   unsigned short* __restrict__ hi,
                                                   unsigned short* __restrict__ lo,
                                                   int R, int C) {
    __shared__ float T[64][65];
    const int r0 = blockIdx.x * 64, c0 = blockIdx.y * 64;
    const int tr = threadIdx.x >> 6, tc = threadIdx.x & 63;
#pragma unroll
    for (int i = 0; i < 16; ++i)
        T[tr + i * 4][tc] = in[(size_t)(r0 + tr + i * 4) * C + c0 + tc];
    __syncthreads();
    const int rr = tc;
#pragma unroll
    for (int i = 0; i < 16; ++i) {
        int cc = tr + i * 4;
        float v = T[rr][cc];
        unsigned short h = f2bf(v);
        hi[(size_t)(c0 + cc) * R + r0 + rr] = h;
        lo[(size_t)(c0 + cc) * R + r0 + rr] = f2bf(v - bf2f(h));
    }
}

// ---------------------------------------------------------------------------
// Kernel 3: elementwise split-convert fp32 -> hi/lo bf16 (as ushort).
// ---------------------------------------------------------------------------
__global__ __launch_bounds__(256) void k_conv(const float* __restrict__ in,
                                              unsigned short* __restrict__ hi,
                                              unsigned short* __restrict__ lo,
                                              int n4) {
    int i = blockIdx.x * 256 + threadIdx.x;
    if (i >= n4) return;
    float4 v = ((const float4*)in)[i];
    ushort4 h, l;
    h.x = f2bf(v.x); l.x = f2bf(v.x - bf2f(h.x));
    h.y = f2bf(v.y); l.y = f2bf(v.y - bf2f(h.y));
    h.z = f2bf(v.z); l.z = f2bf(v.z - bf2f(h.z));
    h.w = f2bf(v.w); l.w = f2bf(v.w - bf2f(h.w));
    ((ushort4*)hi)[i] = h;
    ((ushort4*)lo)[i] = l;
}

// ---------------------------------------------------------------------------
// 256x256 8-phase bf16 GEMM template (T3+T4+T5+T2), bf16x3 via K' = 3K:
// A' = [Ah | Al | Ah], B' = [Bh ; Bh ; Bl]  =>  AhBh + AlBh + AhBl.
// 512 thr = 8 waves (2M x 4N), per-wave C = 128x64 (acc[8][4]).
// LDS: 2 dbuf x 256x64 bf16 per matrix = 128 KiB. BK=64.
// Staging: 4 half-tile ops per K-tile (A0,B0,A1,B1), each 2 gl16/thread,
// issued one phase each during the PREVIOUS tile's compute.
// 16B-block XOR swizzle (blk ^= row&7): inverse-swizzled global source,
// linear gl16 dest, swizzled ds_read -> 2-way banks (free).
// vmcnt ledger: steady-state in-flight at ph0 wait = 8 -> vmcnt(2) keeps
// only the just-issued next-tile op; last iter vmcnt(0). Raw s_barrier
// (no implicit drain) once per phase.
// ---------------------------------------------------------------------------
__device__ __forceinline__ void stage_ht(const unsigned short* __restrict__ src,
                                         unsigned short* lds, int t, int K, int k0) {
#pragma unroll
    for (int j = 0; j < 2; ++j) {
        int slot = j * 512 + t;            // 1024 slots x 16B = 128x64 bf16
        int row = slot >> 3, blk = slot & 7;
        int c = blk ^ (row & 7);           // logical chunk at this phys slot
        gl16(src + (size_t)row * K + k0 + c * 8, lds + slot * 8);
    }
}

#define G8_PHASE(mh, nh)                                                      \
    {                                                                         \
        short8 afr[4][2], bfr[2][2];                                          \
        _Pragma("unroll") for (int i = 0; i < 4; ++i)                         \
            _Pragma("unroll") for (int ks = 0; ks < 2; ++ks) {                \
                int ra = wm + ((mh) * 4 + i) * 16 + r;                        \
                afr[i][ks] = *(const short8*)&Ac[ra * 64 +                    \
                    ((((ks << 2) | q) ^ (ra & 7)) << 3)];                     \
            }                                                                 \
        _Pragma("unroll") for (int j = 0; j < 2; ++j)                         \
            _Pragma("unroll") for (int ks = 0; ks < 2; ++ks) {                \
                int rb = wn + ((nh) * 2 + j) * 16 + r;                        \
                bfr[j][ks] = *(const short8*)&Bc[rb * 64 +                    \
                    ((((ks << 2) | q) ^ (rb & 7)) << 3)];                     \
            }                                                                 \
        __builtin_amdgcn_s_setprio(1);                                        \
        _Pragma("unroll") for (int i = 0; i < 4; ++i)                         \
            _Pragma("unroll") for (int j = 0; j < 2; ++j)                     \
                _Pragma("unroll") for (int ks = 0; ks < 2; ++ks)              \
                    acc[(mh) * 4 + i][(nh) * 2 + j] =                         \
                        __builtin_amdgcn_mfma_f32_16x16x32_bf16(              \
                            afr[i][ks], bfr[j][ks],                           \
                            acc[(mh) * 4 + i][(nh) * 2 + j], 0, 0, 0);        \
        __builtin_amdgcn_s_setprio(0);                                        \
    }

#define G8_MAIN(Ahg, Alg, Bhg, Blg, K_)                                       \
    const int t = threadIdx.x;                                                \
    const int nwg = (int)gridDim.x;                                           \
    const int lin = (int)blockIdx.x;                                          \
    const int cpx = nwg >> 3;                                                 \
    const int lin2 = (lin & 7) * cpx + (lin >> 3);                            \
    const int bm = lin2 & 31, bn = lin2 >> 5;                                 \
    const size_t m0 = (size_t)bm * 256, n0 = (size_t)bn * 256;                \
    const int w = t >> 6, l = t & 63;                                         \
    const int wm = (w & 1) * 128, wn = (w >> 1) * 64;                         \
    const int r = l & 15, q = l >> 4;                                         \
    f32x4 acc[8][4] = {};                                                     \
    const int K = (K_);                                                       \
    const int NT0 = K / 64, NT = 3 * NT0;                                     \
    /* prologue: stage K-tile 0 (seg 0 -> Ah, Bh) */                          \
    stage_ht(Ahg + m0 * K, Ab[0], t, K, 0);                                   \
    stage_ht(Bhg + n0 * K, Bb[0], t, K, 0);                                   \
    stage_ht(Ahg + (m0 + 128) * K, Ab[0] + 128 * 64, t, K, 0);                \
    stage_ht(Bhg + (n0 + 128) * K, Bb[0] + 128 * 64, t, K, 0);                \
    int cur = 0;                                                              \
    for (int kt = 0; kt < NT; ++kt) {                                         \
        const int nk = kt + 1;                                                \
        const bool has_next = nk < NT;                                        \
        const int nseg = nk >= 2 * NT0 ? 2 : (nk >= NT0 ? 1 : 0);             \
        const int nk0 = (nk - nseg * NT0) * 64;                               \
        const unsigned short* Asrc = (nseg == 1) ? (Alg) : (Ahg);             \
        const unsigned short* Bsrc = (nseg == 2) ? (Blg) : (Bhg);             \
        unsigned short* An = Ab[cur ^ 1];                                     \
        unsigned short* Bn = Bb[cur ^ 1];                                     \
        const unsigned short* Ac = Ab[cur];                                   \
        const unsigned short* Bc = Bb[cur];                                   \
        /* ph0 */                                                             \
        if (has_next) {                                                       \
            stage_ht(Asrc + m0 * K, An, t, K, nk0);                           \
            asm volatile("s_waitcnt vmcnt(2)" ::: "memory");                  \
        } else {                                                              \
            asm volatile("s_waitcnt vmcnt(0)" ::: "memory");                  \
        }                                                                     \
        __builtin_amdgcn_s_barrier();                                         \
        G8_PHASE(0, 0)                                                        \
        __builtin_amdgcn_s_barrier();                                         \
        /* ph1 */                                                             \
        if (has_next) stage_ht(Bsrc + n0 * K, Bn, t, K, nk0);                 \
        G8_PHASE(1, 0)                                                        \
        __builtin_amdgcn_s_barrier();                                         \
        /* ph2 */                                                             \
        if (has_next) stage_ht(Asrc + (m0 + 128) * K, An + 128 * 64, t, K, nk0); \
        G8_PHASE(0, 1)                                                        \
        __builtin_amdgcn_s_barrier();                                         \
        /* ph3 */                                                             \
        if (has_next) stage_ht(Bsrc + (n0 + 128) * K, Bn + 128 * 64, t, K, nk0); \
        G8_PHASE(1, 1)                                                        \
        cur ^= 1;                                                             \
    }

// ---------------------------------------------------------------------------
// Kernel 4: 8-phase bf16x3 GEMM -> QKV in attention-ready formats.
// M=8192, N'=1536 (Q,K cols 0..1023 hi/lo row-major; V cols -> vT transposed).
// ---------------------------------------------------------------------------
__global__ __launch_bounds__(512) void k_gemm8_qkv(
        const unsigned short* __restrict__ Ahg, const unsigned short* __restrict__ Alg,
        const unsigned short* __restrict__ Bhg, const unsigned short* __restrict__ Blg,
        unsigned short* __restrict__ qkh, unsigned short* __restrict__ qkl,
        unsigned short* __restrict__ vT) {
    __shared__ unsigned short Ab[2][256 * 64];
    __shared__ unsigned short Bb[2][256 * 64];

    G8_MAIN(Ahg, Alg, Bhg, Blg, DMODEL)

    if (n0 < 1024) {   // Q,K columns -> hi/lo split, row-major
#pragma unroll
        for (int i = 0; i < 8; ++i)
#pragma unroll
            for (int j = 0; j < 4; ++j) {
                int col = (int)n0 + wn + j * 16 + r;
                size_t rowb = m0 + wm + i * 16 + q * 4;
#pragma unroll
                for (int e = 0; e < 4; ++e) {
                    float v = acc[i][j][e];
                    unsigned short h = f2bf(v);
                    qkh[(rowb + e) * 1024 + col] = h;
                    qkl[(rowb + e) * 1024 + col] = f2bf(v - bf2f(h));
                }
            }
    } else {           // V columns -> bf16, transposed [d][row]
#pragma unroll
        for (int i = 0; i < 8; ++i)
#pragma unroll
            for (int j = 0; j < 4; ++j) {
                int d = (int)n0 - 1024 + wn + j * 16 + r;
                size_t rowb = m0 + wm + i * 16 + q * 4;
                ushort4 pk;
                pk.x = f2bf(acc[i][j][0]); pk.y = f2bf(acc[i][j][1]);
                pk.z = f2bf(acc[i][j][2]); pk.w = f2bf(acc[i][j][3]);
                *(ushort4*)&vT[(size_t)d * MROWS + rowb] = pk;
            }
    }
}

// ---------------------------------------------------------------------------
// Kernel 6: 8-phase bf16x3 GEMM, fp32 C (output projection).
// M=8192, N=2048, K'=3*512.
// ---------------------------------------------------------------------------
__global__ __launch_bounds__(512) void k_gemm8_out(
        const unsigned short* __restrict__ Ahg, const unsigned short* __restrict__ Alg,
        const unsigned short* __restrict__ Bhg, const unsigned short* __restrict__ Blg,
        float* __restrict__ C) {
    __shared__ unsigned short Ab[2][256 * 64];
    __shared__ unsigned short Bb[2][256 * 64];

    G8_MAIN(Ahg, Alg, Bhg, Blg, KVDIM)

#pragma unroll
    for (int i = 0; i < 8; ++i)
#pragma unroll
        for (int j = 0; j < 4; ++j) {
            int col = (int)n0 + wn + j * 16 + r;
            size_t rowb = m0 + wm + i * 16 + q * 4;
#pragma unroll
            for (int e = 0; e < 4; ++e)
                C[(rowb + e) * DMODEL + col] = acc[i][j][e];
        }
}

// ---------------------------------------------------------------------------
// Kernel 5: MFMA flash attention (unchanged from R5).
// ---------------------------------------------------------------------------
__global__ __launch_bounds__(256) void k_attn_mfma(
        const unsigned short* __restrict__ qkh, const unsigned short* __restrict__ qkl,
        const unsigned short* __restrict__ vT,
        unsigned short* __restrict__ zh, unsigned short* __restrict__ zl) {
    __shared__ unsigned short Ksh[64 * 64], Ksl[64 * 64], Vt[64 * 64];
    __shared__ unsigned short Pt[4 * 64 * 16];   // per-wave 2KB

    const int t  = threadIdx.x;
    const int w  = t >> 6, l = t & 63;
    const int qt = 31 - blockIdx.x;   // big tiles first
    const int n  = blockIdx.y, b = blockIdx.z;
    const int r  = l & 15, g = l >> 4;
    const int wq0 = w * 16;
    const size_t qrow0 = (size_t)(b * SLEN + qt * 64);

    short8 qh[2], ql[2];
#pragma unroll
    for (int ks = 0; ks < 2; ++ks) {
        size_t off = (qrow0 + wq0 + r) * 1024 + n * 64 + ks * 32 + g * 8;
        qh[ks] = *(const short8*)(qkh + off);
        ql[ks] = *(const short8*)(qkl + off);
    }

    float m_[4], lsum[4];
#pragma unroll
    for (int e = 0; e < 4; ++e) { m_[e] = -3.0e38f; lsum[e] = 0.0f; }
    f32x4 accz[4] = {};

    const int sr = t >> 2, sb = t & 3;

    for (int kt = 0; kt <= qt; ++kt) {
        const size_t krow0 = (size_t)(b * SLEN + kt * 64);
        __syncthreads();
#pragma unroll
        for (int hf = 0; hf < 2; ++hf) {
            int bk = sb + hf * 4;
            size_t goff = (krow0 + sr) * 1024 + 512 + n * 64 + bk * 8;
            short8 kh8 = *(const short8*)(qkh + goff);
            short8 kl8 = *(const short8*)(qkl + goff);
            short8 v8  = *(const short8*)(vT + (size_t)(n * 64 + sr) * MROWS + krow0 + bk * 8);
            int swb = sr * 128 + ((bk ^ (sr & 7)) << 4);
            *(short8*)((char*)Ksh + swb) = kh8;
            *(short8*)((char*)Ksl + swb) = kl8;
            *(short8*)((char*)Vt + swb)  = v8;
        }
        __syncthreads();

        f32x4 s[4] = {};
#pragma unroll
        for (int ct = 0; ct < 4; ++ct)
#pragma unroll
            for (int ks = 0; ks < 2; ++ks) {
                int row = ct * 16 + r;
                int off = row * 128 + (((ks * 4 + g) ^ (row & 7)) << 4);
                short8 kh8 = *(const short8*)((char*)Ksh + off);
                short8 kl8 = *(const short8*)((char*)Ksl + off);
                s[ct] = __builtin_amdgcn_mfma_f32_16x16x32_bf16(qh[ks], kh8, s[ct], 0, 0, 0);
                s[ct] = __builtin_amdgcn_mfma_f32_16x16x32_bf16(ql[ks], kh8, s[ct], 0, 0, 0);
                s[ct] = __builtin_amdgcn_mfma_f32_16x16x32_bf16(qh[ks], kl8, s[ct], 0, 0, 0);
            }

#pragma unroll
        for (int ct = 0; ct < 4; ++ct)
#pragma unroll
            for (int e = 0; e < 4; ++e) {
                float sv = s[ct][e] * 0.125f;
                if (kt == qt && (ct * 16 + r) > (wq0 + g * 4 + e))
                    sv = -100000.0f;
                s[ct][e] = sv;
            }

        float al[4], nm[4];
#pragma unroll
        for (int e = 0; e < 4; ++e) {
            float pm = fmaxf(fmaxf(s[0][e], s[1][e]), fmaxf(s[2][e], s[3][e]));
            pm = fmaxf(pm, __shfl_xor(pm, 1));
            pm = fmaxf(pm, __shfl_xor(pm, 2));
            pm = fmaxf(pm, __shfl_xor(pm, 4));
            pm = fmaxf(pm, __shfl_xor(pm, 8));
            nm[e] = fmaxf(m_[e], pm);
            al[e] = __expf(m_[e] - nm[e]);
            m_[e] = nm[e];
        }

        float ps[4] = {};
#pragma unroll
        for (int ct = 0; ct < 4; ++ct) {
            float p0 = __expf(s[ct][0] - nm[0]);
            float p1 = __expf(s[ct][1] - nm[1]);
            float p2 = __expf(s[ct][2] - nm[2]);
            float p3 = __expf(s[ct][3] - nm[3]);
            ps[0] += p0; ps[1] += p1; ps[2] += p2; ps[3] += p3;
            short4v pk = { (short)f2bf(p0), (short)f2bf(p1),
                           (short)f2bf(p2), (short)f2bf(p3) };
            int kv = ct * 16 + r;
            int phys = (kv >> 5) * 32 + (((kv >> 2) & 1) << 4)
                     + (((kv >> 3) & 3) << 2) + (kv & 3);
            *(short4v*)((char*)Pt + w * 2048 + phys * 32 + g * 8) = pk;
        }

#pragma unroll
        for (int e = 0; e < 4; ++e) {
            float rs = ps[e];
            rs += __shfl_xor(rs, 1); rs += __shfl_xor(rs, 2);
            rs += __shfl_xor(rs, 4); rs += __shfl_xor(rs, 8);
            lsum[e] = lsum[e] * al[e] + rs;
        }

        int src = (r >> 2) << 4;
        float a0 = __shfl(al[0], src), a1 = __shfl(al[1], src);
        float a2 = __shfl(al[2], src), a3 = __shfl(al[3], src);
        float ax = (r & 1) ? a1 : a0, ay = (r & 1) ? a3 : a2;
        float aq = (r & 2) ? ay : ax;
#pragma unroll
        for (int dt = 0; dt < 4; ++dt) {
            accz[dt][0] *= aq; accz[dt][1] *= aq;
            accz[dt][2] *= aq; accz[dt][3] *= aq;
        }

        asm volatile("s_waitcnt lgkmcnt(0)" ::: "memory");
        __builtin_amdgcn_sched_barrier(0);
#pragma unroll
        for (int ks = 0; ks < 2; ++ks) {
            unsigned base = (unsigned)(size_t)((char*)Pt + w * 2048 + ks * 1024) + l * 8;
            U64S4 t1, t2;
            asm volatile("ds_read_b64_tr_b16 %0, %1" : "=v"(t1.u) : "v"(base) : "memory");
            asm volatile("ds_read_b64_tr_b16 %0, %1" : "=v"(t2.u) : "v"(base + 512) : "memory");
            asm volatile("s_waitcnt lgkmcnt(0)" ::: "memory");
            __builtin_amdgcn_sched_barrier(0);
            short8 pfrag = { t1.s[0], t1.s[1], t1.s[2], t1.s[3],
                             t2.s[0], t2.s[1], t2.s[2], t2.s[3] };
#pragma unroll
            for (int dt = 0; dt < 4; ++dt) {
                int row = dt * 16 + r;
                int off = row * 128 + (((ks * 4 + g) ^ (row & 7)) << 4);
                short8 vfrag = *(const short8*)((char*)Vt + off);
                accz[dt] = __builtin_amdgcn_mfma_f32_16x16x32_bf16(vfrag, pfrag, accz[dt], 0, 0, 0);
            }
        }
    }

    int src = (r >> 2) << 4;
    float l0 = __shfl(lsum[0], src), l1 = __shfl(lsum[1], src);
    float l2 = __shfl(lsum[2], src), l3 = __shfl(lsum[3], src);
    float lx = (r & 1) ? l1 : l0, ly = (r & 1) ? l3 : l2;
    float inv = 1.0f / ((r & 2) ? ly : lx);
#pragma unroll
    for (int dt = 0; dt < 4; ++dt) {
        ushort4 h4, l4;
#pragma unroll
        for (int e = 0; e < 4; ++e) {
            float z = accz[dt][e] * inv;
            unsigned short hh = f2bf(z);
            ((unsigned short*)&h4)[e] = hh;
            ((unsigned short*)&l4)[e] = f2bf(z - bf2f(hh));
        }
        size_t off = (qrow0 + wq0 + r) * 512 + n * 64 + dt * 16 + g * 4;
        *(ushort4*)(zh + off) = h4;
        *(ushort4*)(zl + off) = l4;
    }
}

// ---------------------------------------------------------------------------
// Workspace (bytes, 120 MB total):
//   0        : xh 32M      -> after gemm1: zh 8M (at 0), zl 8M (at 8M)
//   32M      : xl 32M
//   64M      : qkh 16M     (first 12M doubles as wcat fp32 before gemm1)
//   80M      : qkl 16M
//   96M      : vT   8M
//   104M     : wcatTh 6M   110M: wcatTl 6M   116M: woTh 2M   118M: woTl 2M
// ---------------------------------------------------------------------------
extern "C" void kernel_launch(void* const* d_in, const int* in_sizes, int n_in,
                              void* d_out, int out_size, void* d_ws, size_t ws_size,
                              hipStream_t stream) {
    const float* x  = (const float*)d_in[0];
    const float* wq = (const float*)d_in[1];
    const float* wk = (const float*)d_in[2];
    const float* wv = (const float*)d_in[3];
    const float* wo = (const float*)d_in[4];
    float* out = (float*)d_out;

    char* w = (char*)d_ws;
    unsigned short* xh = (unsigned short*)(w);
    unsigned short* xl = (unsigned short*)(w + 33554432);
    unsigned short* zh = (unsigned short*)(w);
    unsigned short* zl = (unsigned short*)(w + 8388608);
    unsigned short* qkh = (unsigned short*)(w + 67108864);
    unsigned short* qkl = (unsigned short*)(w + 83886080);
    unsigned short* vT  = (unsigned short*)(w + 100663296);
    float*          wcat   = (float*)(w + 67108864);
    unsigned short* wcatTh = (unsigned short*)(w + 109051904);
    unsigned short* wcatTl = (unsigned short*)(w + 115343360);
    unsigned short* woTh   = (unsigned short*)(w + 121634816);
    unsigned short* woTl   = (unsigned short*)(w + 123731968);

    k_pack<<<dim3((DMODEL * QKV + 255) / 256), 256, 0, stream>>>(wq, wk, wv, wcat);
    k_transconv<<<dim3(32, 24), 256, 0, stream>>>(wcat, wcatTh, wcatTl, DMODEL, QKV);
    k_transconv<<<dim3(8, 32), 256, 0, stream>>>(wo, woTh, woTl, KVDIM, DMODEL);
    k_conv<<<dim3(16384), 256, 0, stream>>>(x, xh, xl, MROWS * DMODEL / 4);
    k_gemm8_qkv<<<dim3(192), 512, 0, stream>>>(xh, xl, wcatTh, wcatTl,
                                               qkh, qkl, vT);
    k_attn_mfma<<<dim3(32, NKV, BATCH), 256, 0, stream>>>(qkh, qkl, vT, zh, zl);
    k_gemm8_out<<<dim3(256), 512, 0, stream>>>(zh, zl, woTh, woTl, out);
}

// Round 7
// 446.107 us; speedup vs baseline: 1.2618x; 1.2618x over previous
//
#include <hip/hip_runtime.h>

typedef __attribute__((ext_vector_type(8))) short short8;
typedef __attribute__((ext_vector_type(4))) short short4v;
typedef __attribute__((ext_vector_type(4))) float f32x4;

#define BATCH  4
#define SLEN   2048
#define DMODEL 2048
#define NKV    8
#define GRP    4
#define DH     64
#define QKV    1536
#define KVDIM  512
#define MROWS  (BATCH * SLEN)   // 8192

// ---- bf16 helpers (RNE) ----------------------------------------------------
__device__ __forceinline__ unsigned short f2bf(float f) {
    unsigned u = __float_as_uint(f);
    u += 0x7FFFu + ((u >> 16) & 1u);
    return (unsigned short)(u >> 16);
}
__device__ __forceinline__ float bf2f(unsigned short h) {
    return __uint_as_float(((unsigned)h) << 16);
}

// ---- async global->LDS, 16B per lane ---------------------------------------
__device__ __forceinline__ void gl16(const void* g, void* l) {
    __builtin_amdgcn_global_load_lds(
        (const __attribute__((address_space(1))) void*)g,
        (__attribute__((address_space(3))) void*)l, 16, 0, 0);
}

union U64S4 { unsigned long long u; short4v s; };

// ---------------------------------------------------------------------------
// Kernel 1: pack weights into Wcat[d_model][1536] (fp32).
// ---------------------------------------------------------------------------
__global__ __launch_bounds__(256) void k_pack(const float* __restrict__ wq,
                                              const float* __restrict__ wk,
                                              const float* __restrict__ wv,
                                              float* __restrict__ wcat) {
    int i = blockIdx.x * 256 + threadIdx.x;
    if (i >= DMODEL * QKV) return;
    int d = i / QKV, c = i - d * QKV;
    int mat = c >> 9, rem = c & 511;
    int n = rem >> 6, h = rem & 63;
    float val;
    if (mat == 0) {
        val = 0.0f;
#pragma unroll
        for (int g = 0; g < GRP; ++g)
            val += wq[((size_t)(n * GRP + g) * DMODEL + d) * DH + h];
    } else if (mat == 1) {
        val = wk[((size_t)n * DMODEL + d) * DH + h];
    } else {
        val = wv[((size_t)n * DMODEL + d) * DH + h];
    }
    wcat[(size_t)d * QKV + c] = val;
}

// ---------------------------------------------------------------------------
// Kernel 2: transpose + split-convert. in fp32 [R][C] -> hi/lo ushort [C][R].
// ---------------------------------------------------------------------------
__global__ __launch_bounds__(256) void k_transconv(const float* __restrict__ in,
                                                   unsigned short* __restrict__ hi,
                                                   unsigned short* __restrict__ lo,
                                                   int R, int C) {
    __shared__ float T[64][65];
    const int r0 = blockIdx.x * 64, c0 = blockIdx.y * 64;
    const int tr = threadIdx.x >> 6, tc = threadIdx.x & 63;
#pragma unroll
    for (int i = 0; i < 16; ++i)
        T[tr + i * 4][tc] = in[(size_t)(r0 + tr + i * 4) * C + c0 + tc];
    __syncthreads();
    const int rr = tc;
#pragma unroll
    for (int i = 0; i < 16; ++i) {
        int cc = tr + i * 4;
        float v = T[rr][cc];
        unsigned short h = f2bf(v);
        hi[(size_t)(c0 + cc) * R + r0 + rr] = h;
        lo[(size_t)(c0 + cc) * R + r0 + rr] = f2bf(v - bf2f(h));
    }
}

// ---------------------------------------------------------------------------
// Kernel 3: elementwise split-convert fp32 -> hi/lo bf16 (as ushort).
// ---------------------------------------------------------------------------
__global__ __launch_bounds__(256) void k_conv(const float* __restrict__ in,
                                              unsigned short* __restrict__ hi,
                                              unsigned short* __restrict__ lo,
                                              int n4) {
    int i = blockIdx.x * 256 + threadIdx.x;
    if (i >= n4) return;
    float4 v = ((const float4*)in)[i];
    ushort4 h, l;
    h.x = f2bf(v.x); l.x = f2bf(v.x - bf2f(h.x));
    h.y = f2bf(v.y); l.y = f2bf(v.y - bf2f(h.y));
    h.z = f2bf(v.z); l.z = f2bf(v.z - bf2f(h.z));
    h.w = f2bf(v.w); l.w = f2bf(v.w - bf2f(h.w));
    ((ushort4*)hi)[i] = h;
    ((ushort4*)lo)[i] = l;
}

// ---------------------------------------------------------------------------
// 256x256 phase-pipelined bf16 GEMM (T2+T3+T4+T5), bf16x3 via K' = 3K:
// A' = [Ah | Al | Ah], B' = [Bh ; Bh ; Bl]  =>  AhBh + AlBh + AhBl.
// 512 thr = 8 waves (2M x 4N), per-wave C = 128x64 (acc[8][4]).
// LDS: 2 dbuf x 256x64 bf16 per matrix = 128 KiB. BK=64.
//
// Per K-tile schedule (R6 post-mortem fix):
//   vmcnt(0)          <- drains this tile's 8 loads, issued ONE FULL TILE ago
//   s_barrier         <- prev tile's reads provably done; cur^1 buffer dead
//   stage 4 half-tiles of t+1 (8 gl16, burst)  <- ~full tile of latency cover
//   Gray-code quadrant walk (0,0)->(0,1)->(1,1)->(1,0), reloading only the
//   changed operand (12+4+8+4 ds_read_b128), s_barrier between phases,
//   setprio(1) around each 16-MFMA cluster.
// 16B-block XOR swizzle (blk ^= row&7): inverse-swizzled global source,
// linear gl16 dest, swizzled ds_read -> measured 0 conflicts (R5/R6).
// ---------------------------------------------------------------------------
__device__ __forceinline__ void stage_ht(const unsigned short* __restrict__ src,
                                         unsigned short* lds, int t, int K, int k0) {
#pragma unroll
    for (int j = 0; j < 2; ++j) {
        int slot = j * 512 + t;            // 1024 slots x 16B = 128x64 bf16
        int row = slot >> 3, blk = slot & 7;
        int c = blk ^ (row & 7);           // logical chunk at this phys slot
        gl16(src + (size_t)row * K + k0 + c * 8, lds + slot * 8);
    }
}

#define LOAD_A(mh)                                                            \
    _Pragma("unroll") for (int i = 0; i < 4; ++i)                             \
        _Pragma("unroll") for (int ks = 0; ks < 2; ++ks) {                    \
            int ra = wm + ((mh) * 4 + i) * 16 + r;                            \
            afr[i][ks] = *(const short8*)&Ac[ra * 64 +                        \
                ((((ks << 2) | q) ^ (ra & 7)) << 3)];                         \
        }

#define LOAD_B(nh)                                                            \
    _Pragma("unroll") for (int j = 0; j < 2; ++j)                             \
        _Pragma("unroll") for (int ks = 0; ks < 2; ++ks) {                    \
            int rb = wn + ((nh) * 2 + j) * 16 + r;                            \
            bfr[j][ks] = *(const short8*)&Bc[rb * 64 +                        \
                ((((ks << 2) | q) ^ (rb & 7)) << 3)];                         \
        }

#define MFMA_Q(mh, nh)                                                        \
    __builtin_amdgcn_s_setprio(1);                                            \
    _Pragma("unroll") for (int i = 0; i < 4; ++i)                             \
        _Pragma("unroll") for (int j = 0; j < 2; ++j)                         \
            _Pragma("unroll") for (int ks = 0; ks < 2; ++ks)                  \
                acc[(mh) * 4 + i][(nh) * 2 + j] =                             \
                    __builtin_amdgcn_mfma_f32_16x16x32_bf16(                  \
                        afr[i][ks], bfr[j][ks],                               \
                        acc[(mh) * 4 + i][(nh) * 2 + j], 0, 0, 0);            \
    __builtin_amdgcn_s_setprio(0);

#define G8_MAIN(Ahg, Alg, Bhg, Blg, K_)                                       \
    const int t = threadIdx.x;                                                \
    const int nwg = (int)gridDim.x;                                           \
    const int lin = (int)blockIdx.x;                                          \
    const int cpx = nwg >> 3;                                                 \
    const int lin2 = (lin & 7) * cpx + (lin >> 3);                            \
    const int bm = lin2 & 31, bn = lin2 >> 5;                                 \
    const size_t m0 = (size_t)bm * 256, n0 = (size_t)bn * 256;                \
    const int w = t >> 6, l = t & 63;                                         \
    const int wm = (w & 1) * 128, wn = (w >> 1) * 64;                         \
    const int r = l & 15, q = l >> 4;                                         \
    f32x4 acc[8][4] = {};                                                     \
    const int K = (K_);                                                       \
    const int NT0 = K / 64, NT = 3 * NT0;                                     \
    /* prologue: stage K-tile 0 (seg 0 -> Ah, Bh) */                          \
    stage_ht(Ahg + m0 * K, Ab[0], t, K, 0);                                   \
    stage_ht(Bhg + n0 * K, Bb[0], t, K, 0);                                   \
    stage_ht(Ahg + (m0 + 128) * K, Ab[0] + 128 * 64, t, K, 0);                \
    stage_ht(Bhg + (n0 + 128) * K, Bb[0] + 128 * 64, t, K, 0);                \
    int cur = 0;                                                              \
    for (int kt = 0; kt < NT; ++kt) {                                         \
        const int nk = kt + 1;                                                \
        const bool has_next = nk < NT;                                        \
        const int nseg = nk >= 2 * NT0 ? 2 : (nk >= NT0 ? 1 : 0);             \
        const int nk0 = (nk - nseg * NT0) * 64;                               \
        const unsigned short* Asrc = (nseg == 1) ? (Alg) : (Ahg);             \
        const unsigned short* Bsrc = (nseg == 2) ? (Blg) : (Bhg);             \
        const unsigned short* Ac = Ab[cur];                                   \
        const unsigned short* Bc = Bb[cur];                                   \
        asm volatile("s_waitcnt vmcnt(0)" ::: "memory");                      \
        __builtin_amdgcn_s_barrier();                                         \
        if (has_next) {                                                       \
            unsigned short* An = Ab[cur ^ 1];                                 \
            unsigned short* Bn = Bb[cur ^ 1];                                 \
            stage_ht(Asrc + m0 * K, An, t, K, nk0);                           \
            stage_ht(Bsrc + n0 * K, Bn, t, K, nk0);                           \
            stage_ht(Asrc + (m0 + 128) * K, An + 128 * 64, t, K, nk0);        \
            stage_ht(Bsrc + (n0 + 128) * K, Bn + 128 * 64, t, K, nk0);        \
        }                                                                     \
        short8 afr[4][2], bfr[2][2];                                          \
        LOAD_A(0) LOAD_B(0)                                                   \
        MFMA_Q(0, 0)                                                          \
        __builtin_amdgcn_s_barrier();                                         \
        LOAD_B(1)                                                             \
        MFMA_Q(0, 1)                                                          \
        __builtin_amdgcn_s_barrier();                                         \
        LOAD_A(1)                                                             \
        MFMA_Q(1, 1)                                                          \
        __builtin_amdgcn_s_barrier();                                         \
        LOAD_B(0)                                                             \
        MFMA_Q(1, 0)                                                          \
        cur ^= 1;                                                             \
    }

// ---------------------------------------------------------------------------
// Kernel 4: pipelined bf16x3 GEMM -> QKV in attention-ready formats.
// M=8192, N'=1536 (Q,K cols 0..1023 hi/lo row-major; V cols -> vT transposed).
// ---------------------------------------------------------------------------
__global__ __launch_bounds__(512) void k_gemm8_qkv(
        const unsigned short* __restrict__ Ahg, const unsigned short* __restrict__ Alg,
        const unsigned short* __restrict__ Bhg, const unsigned short* __restrict__ Blg,
        unsigned short* __restrict__ qkh, unsigned short* __restrict__ qkl,
        unsigned short* __restrict__ vT) {
    __shared__ unsigned short Ab[2][256 * 64];
    __shared__ unsigned short Bb[2][256 * 64];

    G8_MAIN(Ahg, Alg, Bhg, Blg, DMODEL)

    if (n0 < 1024) {   // Q,K columns -> hi/lo split, row-major
#pragma unroll
        for (int i = 0; i < 8; ++i)
#pragma unroll
            for (int j = 0; j < 4; ++j) {
                int col = (int)n0 + wn + j * 16 + r;
                size_t rowb = m0 + wm + i * 16 + q * 4;
#pragma unroll
                for (int e = 0; e < 4; ++e) {
                    float v = acc[i][j][e];
                    unsigned short h = f2bf(v);
                    qkh[(rowb + e) * 1024 + col] = h;
                    qkl[(rowb + e) * 1024 + col] = f2bf(v - bf2f(h));
                }
            }
    } else {           // V columns -> bf16, transposed [d][row]
#pragma unroll
        for (int i = 0; i < 8; ++i)
#pragma unroll
            for (int j = 0; j < 4; ++j) {
                int d = (int)n0 - 1024 + wn + j * 16 + r;
                size_t rowb = m0 + wm + i * 16 + q * 4;
                ushort4 pk;
                pk.x = f2bf(acc[i][j][0]); pk.y = f2bf(acc[i][j][1]);
                pk.z = f2bf(acc[i][j][2]); pk.w = f2bf(acc[i][j][3]);
                *(ushort4*)&vT[(size_t)d * MROWS + rowb] = pk;
            }
    }
}

// ---------------------------------------------------------------------------
// Kernel 6: pipelined bf16x3 GEMM, fp32 C (output projection).
// M=8192, N=2048, K'=3*512.
// ---------------------------------------------------------------------------
__global__ __launch_bounds__(512) void k_gemm8_out(
        const unsigned short* __restrict__ Ahg, const unsigned short* __restrict__ Alg,
        const unsigned short* __restrict__ Bhg, const unsigned short* __restrict__ Blg,
        float* __restrict__ C) {
    __shared__ unsigned short Ab[2][256 * 64];
    __shared__ unsigned short Bb[2][256 * 64];

    G8_MAIN(Ahg, Alg, Bhg, Blg, KVDIM)

#pragma unroll
    for (int i = 0; i < 8; ++i)
#pragma unroll
        for (int j = 0; j < 4; ++j) {
            int col = (int)n0 + wn + j * 16 + r;
            size_t rowb = m0 + wm + i * 16 + q * 4;
#pragma unroll
            for (int e = 0; e < 4; ++e)
                C[(rowb + e) * DMODEL + col] = acc[i][j][e];
        }
}

// ---------------------------------------------------------------------------
// Kernel 5: MFMA flash attention (unchanged from R5).
// ---------------------------------------------------------------------------
__global__ __launch_bounds__(256) void k_attn_mfma(
        const unsigned short* __restrict__ qkh, const unsigned short* __restrict__ qkl,
        const unsigned short* __restrict__ vT,
        unsigned short* __restrict__ zh, unsigned short* __restrict__ zl) {
    __shared__ unsigned short Ksh[64 * 64], Ksl[64 * 64], Vt[64 * 64];
    __shared__ unsigned short Pt[4 * 64 * 16];   // per-wave 2KB

    const int t  = threadIdx.x;
    const int w  = t >> 6, l = t & 63;
    const int qt = 31 - blockIdx.x;   // big tiles first
    const int n  = blockIdx.y, b = blockIdx.z;
    const int r  = l & 15, g = l >> 4;
    const int wq0 = w * 16;
    const size_t qrow0 = (size_t)(b * SLEN + qt * 64);

    short8 qh[2], ql[2];
#pragma unroll
    for (int ks = 0; ks < 2; ++ks) {
        size_t off = (qrow0 + wq0 + r) * 1024 + n * 64 + ks * 32 + g * 8;
        qh[ks] = *(const short8*)(qkh + off);
        ql[ks] = *(const short8*)(qkl + off);
    }

    float m_[4], lsum[4];
#pragma unroll
    for (int e = 0; e < 4; ++e) { m_[e] = -3.0e38f; lsum[e] = 0.0f; }
    f32x4 accz[4] = {};

    const int sr = t >> 2, sb = t & 3;

    for (int kt = 0; kt <= qt; ++kt) {
        const size_t krow0 = (size_t)(b * SLEN + kt * 64);
        __syncthreads();
#pragma unroll
        for (int hf = 0; hf < 2; ++hf) {
            int bk = sb + hf * 4;
            size_t goff = (krow0 + sr) * 1024 + 512 + n * 64 + bk * 8;
            short8 kh8 = *(const short8*)(qkh + goff);
            short8 kl8 = *(const short8*)(qkl + goff);
            short8 v8  = *(const short8*)(vT + (size_t)(n * 64 + sr) * MROWS + krow0 + bk * 8);
            int swb = sr * 128 + ((bk ^ (sr & 7)) << 4);
            *(short8*)((char*)Ksh + swb) = kh8;
            *(short8*)((char*)Ksl + swb) = kl8;
            *(short8*)((char*)Vt + swb)  = v8;
        }
        __syncthreads();

        f32x4 s[4] = {};
#pragma unroll
        for (int ct = 0; ct < 4; ++ct)
#pragma unroll
            for (int ks = 0; ks < 2; ++ks) {
                int row = ct * 16 + r;
                int off = row * 128 + (((ks * 4 + g) ^ (row & 7)) << 4);
                short8 kh8 = *(const short8*)((char*)Ksh + off);
                short8 kl8 = *(const short8*)((char*)Ksl + off);
                s[ct] = __builtin_amdgcn_mfma_f32_16x16x32_bf16(qh[ks], kh8, s[ct], 0, 0, 0);
                s[ct] = __builtin_amdgcn_mfma_f32_16x16x32_bf16(ql[ks], kh8, s[ct], 0, 0, 0);
                s[ct] = __builtin_amdgcn_mfma_f32_16x16x32_bf16(qh[ks], kl8, s[ct], 0, 0, 0);
            }

#pragma unroll
        for (int ct = 0; ct < 4; ++ct)
#pragma unroll
            for (int e = 0; e < 4; ++e) {
                float sv = s[ct][e] * 0.125f;
                if (kt == qt && (ct * 16 + r) > (wq0 + g * 4 + e))
                    sv = -100000.0f;
                s[ct][e] = sv;
            }

        float al[4], nm[4];
#pragma unroll
        for (int e = 0; e < 4; ++e) {
            float pm = fmaxf(fmaxf(s[0][e], s[1][e]), fmaxf(s[2][e], s[3][e]));
            pm = fmaxf(pm, __shfl_xor(pm, 1));
            pm = fmaxf(pm, __shfl_xor(pm, 2));
            pm = fmaxf(pm, __shfl_xor(pm, 4));
            pm = fmaxf(pm, __shfl_xor(pm, 8));
            nm[e] = fmaxf(m_[e], pm);
            al[e] = __expf(m_[e] - nm[e]);
            m_[e] = nm[e];
        }

        float ps[4] = {};
#pragma unroll
        for (int ct = 0; ct < 4; ++ct) {
            float p0 = __expf(s[ct][0] - nm[0]);
            float p1 = __expf(s[ct][1] - nm[1]);
            float p2 = __expf(s[ct][2] - nm[2]);
            float p3 = __expf(s[ct][3] - nm[3]);
            ps[0] += p0; ps[1] += p1; ps[2] += p2; ps[3] += p3;
            short4v pk = { (short)f2bf(p0), (short)f2bf(p1),
                           (short)f2bf(p2), (short)f2bf(p3) };
            int kv = ct * 16 + r;
            int phys = (kv >> 5) * 32 + (((kv >> 2) & 1) << 4)
                     + (((kv >> 3) & 3) << 2) + (kv & 3);
            *(short4v*)((char*)Pt + w * 2048 + phys * 32 + g * 8) = pk;
        }

#pragma unroll
        for (int e = 0; e < 4; ++e) {
            float rs = ps[e];
            rs += __shfl_xor(rs, 1); rs += __shfl_xor(rs, 2);
            rs += __shfl_xor(rs, 4); rs += __shfl_xor(rs, 8);
            lsum[e] = lsum[e] * al[e] + rs;
        }

        int src = (r >> 2) << 4;
        float a0 = __shfl(al[0], src), a1 = __shfl(al[1], src);
        float a2 = __shfl(al[2], src), a3 = __shfl(al[3], src);
        float ax = (r & 1) ? a1 : a0, ay = (r & 1) ? a3 : a2;
        float aq = (r & 2) ? ay : ax;
#pragma unroll
        for (int dt = 0; dt < 4; ++dt) {
            accz[dt][0] *= aq; accz[dt][1] *= aq;
            accz[dt][2] *= aq; accz[dt][3] *= aq;
        }

        asm volatile("s_waitcnt lgkmcnt(0)" ::: "memory");
        __builtin_amdgcn_sched_barrier(0);
#pragma unroll
        for (int ks = 0; ks < 2; ++ks) {
            unsigned base = (unsigned)(size_t)((char*)Pt + w * 2048 + ks * 1024) + l * 8;
            U64S4 t1, t2;
            asm volatile("ds_read_b64_tr_b16 %0, %1" : "=v"(t1.u) : "v"(base) : "memory");
            asm volatile("ds_read_b64_tr_b16 %0, %1" : "=v"(t2.u) : "v"(base + 512) : "memory");
            asm volatile("s_waitcnt lgkmcnt(0)" ::: "memory");
            __builtin_amdgcn_sched_barrier(0);
            short8 pfrag = { t1.s[0], t1.s[1], t1.s[2], t1.s[3],
                             t2.s[0], t2.s[1], t2.s[2], t2.s[3] };
#pragma unroll
            for (int dt = 0; dt < 4; ++dt) {
                int row = dt * 16 + r;
                int off = row * 128 + (((ks * 4 + g) ^ (row & 7)) << 4);
                short8 vfrag = *(const short8*)((char*)Vt + off);
                accz[dt] = __builtin_amdgcn_mfma_f32_16x16x32_bf16(vfrag, pfrag, accz[dt], 0, 0, 0);
            }
        }
    }

    int src = (r >> 2) << 4;
    float l0 = __shfl(lsum[0], src), l1 = __shfl(lsum[1], src);
    float l2 = __shfl(lsum[2], src), l3 = __shfl(lsum[3], src);
    float lx = (r & 1) ? l1 : l0, ly = (r & 1) ? l3 : l2;
    float inv = 1.0f / ((r & 2) ? ly : lx);
#pragma unroll
    for (int dt = 0; dt < 4; ++dt) {
        ushort4 h4, l4;
#pragma unroll
        for (int e = 0; e < 4; ++e) {
            float z = accz[dt][e] * inv;
            unsigned short hh = f2bf(z);
            ((unsigned short*)&h4)[e] = hh;
            ((unsigned short*)&l4)[e] = f2bf(z - bf2f(hh));
        }
        size_t off = (qrow0 + wq0 + r) * 512 + n * 64 + dt * 16 + g * 4;
        *(ushort4*)(zh + off) = h4;
        *(ushort4*)(zl + off) = l4;
    }
}

// ---------------------------------------------------------------------------
// Workspace (bytes, 120 MB total):
//   0        : xh 32M      -> after gemm1: zh 8M (at 0), zl 8M (at 8M)
//   32M      : xl 32M
//   64M      : qkh 16M     (first 12M doubles as wcat fp32 before gemm1)
//   80M      : qkl 16M
//   96M      : vT   8M
//   104M     : wcatTh 6M   110M: wcatTl 6M   116M: woTh 2M   118M: woTl 2M
// ---------------------------------------------------------------------------
extern "C" void kernel_launch(void* const* d_in, const int* in_sizes, int n_in,
                              void* d_out, int out_size, void* d_ws, size_t ws_size,
                              hipStream_t stream) {
    const float* x  = (const float*)d_in[0];
    const float* wq = (const float*)d_in[1];
    const float* wk = (const float*)d_in[2];
    const float* wv = (const float*)d_in[3];
    const float* wo = (const float*)d_in[4];
    float* out = (float*)d_out;

    char* w = (char*)d_ws;
    unsigned short* xh = (unsigned short*)(w);
    unsigned short* xl = (unsigned short*)(w + 33554432);
    unsigned short* zh = (unsigned short*)(w);
    unsigned short* zl = (unsigned short*)(w + 8388608);
    unsigned short* qkh = (unsigned short*)(w + 67108864);
    unsigned short* qkl = (unsigned short*)(w + 83886080);
    unsigned short* vT  = (unsigned short*)(w + 100663296);
    float*          wcat   = (float*)(w + 67108864);
    unsigned short* wcatTh = (unsigned short*)(w + 109051904);
    unsigned short* wcatTl = (unsigned short*)(w + 115343360);
    unsigned short* woTh   = (unsigned short*)(w + 121634816);
    unsigned short* woTl   = (unsigned short*)(w + 123731968);

    k_pack<<<dim3((DMODEL * QKV + 255) / 256), 256, 0, stream>>>(wq, wk, wv, wcat);
    k_transconv<<<dim3(32, 24), 256, 0, stream>>>(wcat, wcatTh, wcatTl, DMODEL, QKV);
    k_transconv<<<dim3(8, 32), 256, 0, stream>>>(wo, woTh, woTl, KVDIM, DMODEL);
    k_conv<<<dim3(16384), 256, 0, stream>>>(x, xh, xl, MROWS * DMODEL / 4);
    k_gemm8_qkv<<<dim3(192), 512, 0, stream>>>(xh, xl, wcatTh, wcatTl,
                                               qkh, qkl, vT);
    k_attn_mfma<<<dim3(32, NKV, BATCH), 256, 0, stream>>>(qkh, qkl, vT, zh, zl);
    k_gemm8_out<<<dim3(256), 512, 0, stream>>>(zh, zl, woTh, woTl, out);
}

// Round 8
// 250.867 us; speedup vs baseline: 2.2438x; 1.7783x over previous
//
#include <hip/hip_runtime.h>

typedef __attribute__((ext_vector_type(8))) _Float16 half8;
typedef __attribute__((ext_vector_type(4))) float f32x4;

#define BATCH  4
#define SLEN   2048
#define DMODEL 2048
#define NKV    8
#define GRP    4
#define DH     64
#define QKV    1536
#define KVDIM  512
#define MROWS  (BATCH * SLEN)   // 8192

// ---- fp16 helper (RNE via hardware cvt) ------------------------------------
__device__ __forceinline__ unsigned short f2h(float f) {
    union { _Float16 h; unsigned short u; } cv;
    cv.h = (_Float16)f;
    return cv.u;
}

// ---- async global->LDS, 16B per lane ---------------------------------------
__device__ __forceinline__ void gl16(const void* g, void* l) {
    __builtin_amdgcn_global_load_lds(
        (const __attribute__((address_space(1))) void*)g,
        (__attribute__((address_space(3))) void*)l, 16, 0, 0);
}

typedef __attribute__((ext_vector_type(4))) short short4v;
union U64S4 { unsigned long long u; short4v s; };

// ---------------------------------------------------------------------------
// Kernel 1: pack weights into Wcat[d_model][1536] (fp32).
// cols 0..511: sum_g W_Q (reference sums g in the scores einsum),
// 512..1023: W_K, 1024..1535: W_V.  col = mat*512 + n*64 + h.
// ---------------------------------------------------------------------------
__global__ __launch_bounds__(256) void k_pack(const float* __restrict__ wq,
                                              const float* __restrict__ wk,
                                              const float* __restrict__ wv,
                                              float* __restrict__ wcat) {
    int i = blockIdx.x * 256 + threadIdx.x;
    if (i >= DMODEL * QKV) return;
    int d = i / QKV, c = i - d * QKV;
    int mat = c >> 9, rem = c & 511;
    int n = rem >> 6, h = rem & 63;
    float val;
    if (mat == 0) {
        val = 0.0f;
#pragma unroll
        for (int g = 0; g < GRP; ++g)
            val += wq[((size_t)(n * GRP + g) * DMODEL + d) * DH + h];
    } else if (mat == 1) {
        val = wk[((size_t)n * DMODEL + d) * DH + h];
    } else {
        val = wv[((size_t)n * DMODEL + d) * DH + h];
    }
    wcat[(size_t)d * QKV + c] = val;
}

// ---------------------------------------------------------------------------
// Kernel 2: transpose + fp16 convert. in fp32 [R][C] -> fp16 ushort [C][R].
// ---------------------------------------------------------------------------
__global__ __launch_bounds__(256) void k_transconv_h(const float* __restrict__ in,
                                                     unsigned short* __restrict__ outT,
                                                     int R, int C) {
    __shared__ float T[64][65];
    const int r0 = blockIdx.x * 64, c0 = blockIdx.y * 64;
    const int tr = threadIdx.x >> 6, tc = threadIdx.x & 63;
#pragma unroll
    for (int i = 0; i < 16; ++i)
        T[tr + i * 4][tc] = in[(size_t)(r0 + tr + i * 4) * C + c0 + tc];
    __syncthreads();
    const int rr = tc;
#pragma unroll
    for (int i = 0; i < 16; ++i) {
        int cc = tr + i * 4;
        outT[(size_t)(c0 + cc) * R + r0 + rr] = f2h(T[rr][cc]);
    }
}

// ---------------------------------------------------------------------------
// Kernel 3: elementwise fp32 -> fp16.
// ---------------------------------------------------------------------------
__global__ __launch_bounds__(256) void k_convh(const float* __restrict__ in,
                                               unsigned short* __restrict__ out,
                                               int n4) {
    int i = blockIdx.x * 256 + threadIdx.x;
    if (i >= n4) return;
    float4 v = ((const float4*)in)[i];
    ushort4 o;
    o.x = f2h(v.x); o.y = f2h(v.y); o.z = f2h(v.z); o.w = f2h(v.w);
    ((ushort4*)out)[i] = o;
}

// ---------------------------------------------------------------------------
// Plain-fp16 2-phase MFMA GEMM (R5-proven structure).  C = A[M][K] @ B^T
// where B given pre-transposed [N][K] fp16.  128x128 tile, BK=64, 256 thr
// (4 waves 2x2 of 64x64), 16x16x32 f16 MFMA; per K-step: 8x gl16 stage,
// 16x ds_read_b128, 32 MFMA.  LDS [128 rows][64 cols fp16] = 128B rows =
// 8x16B blocks; phys_blk = logical ^ (row&7) applied on the GLOBAL source
// (gl16 dest linear), compensated on ds_read -> 0 bank conflicts (measured
// R5/R6/R7).  Double-buffered: 64 KiB LDS.
// ---------------------------------------------------------------------------
__device__ __forceinline__ void stage_tile64(const unsigned short* __restrict__ src,
                                             unsigned short* lds, int t, int K, int k0) {
#pragma unroll
    for (int j = 0; j < 4; ++j) {
        int slot = j * 256 + t;            // 1024 slots x 16B = 128x64 fp16
        int row = slot >> 3, blk = slot & 7;
        int c = blk ^ (row & 7);           // logical chunk at this phys slot
        gl16(src + (size_t)row * K + k0 + c * 8, lds + slot * 8);
    }
}

#define GEMMF16_MAIN(Ag, Bg, K_)                                              \
    const int t = threadIdx.x;                                                \
    const size_t m0 = (size_t)blockIdx.x * 128, n0 = (size_t)blockIdx.y * 128;\
    const int w = t >> 6, l = t & 63;                                         \
    const int wm = (w >> 1) * 64, wn = (w & 1) * 64;                          \
    const int r = l & 15, q = l >> 4;                                         \
    f32x4 acc[4][4] = {};                                                     \
    const int K = (K_);                                                       \
    const int NT = K / 64;                                                    \
    stage_tile64(Ag + m0 * K, A2[0], t, K, 0);                                \
    stage_tile64(Bg + n0 * K, B2[0], t, K, 0);                                \
    asm volatile("s_waitcnt vmcnt(0)" ::: "memory");                          \
    __builtin_amdgcn_s_barrier();                                             \
    int cur = 0;                                                              \
    for (int kt = 0; kt < NT; ++kt) {                                         \
        if (kt + 1 < NT) {                                                    \
            stage_tile64(Ag + m0 * K, A2[cur ^ 1], t, K, (kt + 1) * 64);      \
            stage_tile64(Bg + n0 * K, B2[cur ^ 1], t, K, (kt + 1) * 64);      \
        }                                                                     \
        const unsigned short* Ac = A2[cur];                                   \
        const unsigned short* Bc = B2[cur];                                   \
        half8 af[4][2], bf[4][2];                                             \
        _Pragma("unroll") for (int i = 0; i < 4; ++i)                         \
            _Pragma("unroll") for (int ks = 0; ks < 2; ++ks) {                \
                int ra = wm + i * 16 + r;                                     \
                af[i][ks] = *(const half8*)&Ac[ra * 64 +                      \
                    ((((ks << 2) | q) ^ (ra & 7)) << 3)];                     \
                int rb = wn + i * 16 + r;                                     \
                bf[i][ks] = *(const half8*)&Bc[rb * 64 +                      \
                    ((((ks << 2) | q) ^ (rb & 7)) << 3)];                     \
            }                                                                 \
        __builtin_amdgcn_s_setprio(1);                                        \
        _Pragma("unroll") for (int i = 0; i < 4; ++i)                         \
            _Pragma("unroll") for (int j = 0; j < 4; ++j) {                   \
                acc[i][j] = __builtin_amdgcn_mfma_f32_16x16x32_f16(           \
                    af[i][0], bf[j][0], acc[i][j], 0, 0, 0);                  \
                acc[i][j] = __builtin_amdgcn_mfma_f32_16x16x32_f16(           \
                    af[i][1], bf[j][1], acc[i][j], 0, 0, 0);                  \
            }                                                                 \
        __builtin_amdgcn_s_setprio(0);                                        \
        asm volatile("s_waitcnt vmcnt(0)" ::: "memory");                      \
        __builtin_amdgcn_s_barrier();                                         \
        cur ^= 1;                                                             \
    }

// ---------------------------------------------------------------------------
// Kernel 4: fp16 GEMM -> QKV.  A = x fp16 [M][2048]; B = wcatT fp16 [1536][2048].
// Epilogue: cols <1024 (Q,K) -> qk fp16 [M][1024]; cols >=1024 (V) -> vT fp16
// [512][M] (transposed for attention's PV).
// ---------------------------------------------------------------------------
__global__ __launch_bounds__(256) void k_gemm_qkv(
        const unsigned short* __restrict__ Ag, const unsigned short* __restrict__ Bg,
        unsigned short* __restrict__ qk, unsigned short* __restrict__ vT) {
    __shared__ unsigned short A2[2][128 * 64];
    __shared__ unsigned short B2[2][128 * 64];

    GEMMF16_MAIN(Ag, Bg, DMODEL)

    if (n0 < 1024) {   // Q,K columns -> row-major fp16
#pragma unroll
        for (int i = 0; i < 4; ++i)
#pragma unroll
            for (int j = 0; j < 4; ++j) {
                int col = (int)n0 + wn + j * 16 + r;
                size_t rowb = m0 + wm + i * 16 + q * 4;
#pragma unroll
                for (int e = 0; e < 4; ++e)
                    qk[(rowb + e) * 1024 + col] = f2h(acc[i][j][e]);
            }
    } else {           // V columns -> fp16, transposed [d][row]
#pragma unroll
        for (int i = 0; i < 4; ++i)
#pragma unroll
            for (int j = 0; j < 4; ++j) {
                int d = (int)n0 - 1024 + wn + j * 16 + r;
                size_t rowb = m0 + wm + i * 16 + q * 4;
                ushort4 pk;
                pk.x = f2h(acc[i][j][0]); pk.y = f2h(acc[i][j][1]);
                pk.z = f2h(acc[i][j][2]); pk.w = f2h(acc[i][j][3]);
                *(ushort4*)&vT[(size_t)d * MROWS + rowb] = pk;
            }
    }
}

// ---------------------------------------------------------------------------
// Kernel 6: fp16 GEMM, fp32 C (output projection).  A = z fp16 [M][512],
// B = woT fp16 [2048][512].
// ---------------------------------------------------------------------------
__global__ __launch_bounds__(256) void k_gemm_out(
        const unsigned short* __restrict__ Ag, const unsigned short* __restrict__ Bg,
        float* __restrict__ C) {
    __shared__ unsigned short A2[2][128 * 64];
    __shared__ unsigned short B2[2][128 * 64];

    GEMMF16_MAIN(Ag, Bg, KVDIM)

#pragma unroll
    for (int i = 0; i < 4; ++i)
#pragma unroll
        for (int j = 0; j < 4; ++j) {
            int col = (int)n0 + wn + j * 16 + r;
            size_t rowb = m0 + wm + i * 16 + q * 4;
#pragma unroll
            for (int e = 0; e < 4; ++e)
                C[(rowb + e) * DMODEL + col] = acc[i][j][e];
        }
}

// ---------------------------------------------------------------------------
// Kernel 5: fp16 MFMA flash attention (verified R4-R7 structure, fp16 ops).
// Block = 256 thr (4 waves x 16 q-rows) per (b, n, 64-q-tile).
// K staged in LDS with 16B-block XOR swizzle; softmax in-register via
// 16-lane shfl_xor; P -> per-wave LDS (row-permuted) -> exact B-frags via
// ds_read_b64_tr_b16; PV fp16 with V^T staged like K.  LDS 24 KB.
// ---------------------------------------------------------------------------
__global__ __launch_bounds__(256) void k_attn_mfma(
        const unsigned short* __restrict__ qk, const unsigned short* __restrict__ vT,
        unsigned short* __restrict__ zh) {
    __shared__ unsigned short Ksh[64 * 64], Vt[64 * 64];
    __shared__ unsigned short Pt[4 * 64 * 16];   // per-wave 2KB

    const int t  = threadIdx.x;
    const int w  = t >> 6, l = t & 63;
    const int qt = 31 - blockIdx.x;   // big tiles first
    const int n  = blockIdx.y, b = blockIdx.z;
    const int r  = l & 15, g = l >> 4;
    const int wq0 = w * 16;
    const size_t qrow0 = (size_t)(b * SLEN + qt * 64);

    half8 qh[2];
#pragma unroll
    for (int ks = 0; ks < 2; ++ks) {
        size_t off = (qrow0 + wq0 + r) * 1024 + n * 64 + ks * 32 + g * 8;
        qh[ks] = *(const half8*)(qk + off);
    }

    float m_[4], lsum[4];
#pragma unroll
    for (int e = 0; e < 4; ++e) { m_[e] = -3.0e38f; lsum[e] = 0.0f; }
    f32x4 accz[4] = {};

    const int sr = t >> 2, sb = t & 3;

    for (int kt = 0; kt <= qt; ++kt) {
        const size_t krow0 = (size_t)(b * SLEN + kt * 64);
        __syncthreads();
#pragma unroll
        for (int hf = 0; hf < 2; ++hf) {
            int bk = sb + hf * 4;
            size_t goff = (krow0 + sr) * 1024 + 512 + n * 64 + bk * 8;
            ulonglong2 kh8 = *(const ulonglong2*)(qk + goff);
            ulonglong2 v8  = *(const ulonglong2*)(vT + (size_t)(n * 64 + sr) * MROWS + krow0 + bk * 8);
            int swb = sr * 128 + ((bk ^ (sr & 7)) << 4);
            *(ulonglong2*)((char*)Ksh + swb) = kh8;
            *(ulonglong2*)((char*)Vt + swb)  = v8;
        }
        __syncthreads();

        f32x4 s[4] = {};
#pragma unroll
        for (int ct = 0; ct < 4; ++ct)
#pragma unroll
            for (int ks = 0; ks < 2; ++ks) {
                int row = ct * 16 + r;
                int off = row * 128 + (((ks * 4 + g) ^ (row & 7)) << 4);
                half8 kh8 = *(const half8*)((char*)Ksh + off);
                s[ct] = __builtin_amdgcn_mfma_f32_16x16x32_f16(qh[ks], kh8, s[ct], 0, 0, 0);
            }

#pragma unroll
        for (int ct = 0; ct < 4; ++ct)
#pragma unroll
            for (int e = 0; e < 4; ++e) {
                float sv = s[ct][e] * 0.125f;
                if (kt == qt && (ct * 16 + r) > (wq0 + g * 4 + e))
                    sv = -100000.0f;   // reference IGNORE
                s[ct][e] = sv;
            }

        float al[4], nm[4];
#pragma unroll
        for (int e = 0; e < 4; ++e) {
            float pm = fmaxf(fmaxf(s[0][e], s[1][e]), fmaxf(s[2][e], s[3][e]));
            pm = fmaxf(pm, __shfl_xor(pm, 1));
            pm = fmaxf(pm, __shfl_xor(pm, 2));
            pm = fmaxf(pm, __shfl_xor(pm, 4));
            pm = fmaxf(pm, __shfl_xor(pm, 8));
            nm[e] = fmaxf(m_[e], pm);
            al[e] = __expf(m_[e] - nm[e]);
            m_[e] = nm[e];
        }

        float ps[4] = {};
#pragma unroll
        for (int ct = 0; ct < 4; ++ct) {
            float p0 = __expf(s[ct][0] - nm[0]);
            float p1 = __expf(s[ct][1] - nm[1]);
            float p2 = __expf(s[ct][2] - nm[2]);
            float p3 = __expf(s[ct][3] - nm[3]);
            ps[0] += p0; ps[1] += p1; ps[2] += p2; ps[3] += p3;
            short4v pk = { (short)f2h(p0), (short)f2h(p1),
                           (short)f2h(p2), (short)f2h(p3) };
            int kv = ct * 16 + r;
            int phys = (kv >> 5) * 32 + (((kv >> 2) & 1) << 4)
                     + (((kv >> 3) & 3) << 2) + (kv & 3);
            *(short4v*)((char*)Pt + w * 2048 + phys * 32 + g * 8) = pk;
        }

#pragma unroll
        for (int e = 0; e < 4; ++e) {
            float rs = ps[e];
            rs += __shfl_xor(rs, 1); rs += __shfl_xor(rs, 2);
            rs += __shfl_xor(rs, 4); rs += __shfl_xor(rs, 8);
            lsum[e] = lsum[e] * al[e] + rs;
        }

        int src = (r >> 2) << 4;
        float a0 = __shfl(al[0], src), a1 = __shfl(al[1], src);
        float a2 = __shfl(al[2], src), a3 = __shfl(al[3], src);
        float ax = (r & 1) ? a1 : a0, ay = (r & 1) ? a3 : a2;
        float aq = (r & 2) ? ay : ax;
#pragma unroll
        for (int dt = 0; dt < 4; ++dt) {
            accz[dt][0] *= aq; accz[dt][1] *= aq;
            accz[dt][2] *= aq; accz[dt][3] *= aq;
        }

        asm volatile("s_waitcnt lgkmcnt(0)" ::: "memory");
        __builtin_amdgcn_sched_barrier(0);
#pragma unroll
        for (int ks = 0; ks < 2; ++ks) {
            unsigned base = (unsigned)(size_t)((char*)Pt + w * 2048 + ks * 1024) + l * 8;
            U64S4 t1, t2;
            asm volatile("ds_read_b64_tr_b16 %0, %1" : "=v"(t1.u) : "v"(base) : "memory");
            asm volatile("ds_read_b64_tr_b16 %0, %1" : "=v"(t2.u) : "v"(base + 512) : "memory");
            asm volatile("s_waitcnt lgkmcnt(0)" ::: "memory");
            __builtin_amdgcn_sched_barrier(0);
            short4v pa = t1.s, pb = t2.s;
            union { short s[8]; half8 h; } pf;
            pf.s[0] = pa[0]; pf.s[1] = pa[1]; pf.s[2] = pa[2]; pf.s[3] = pa[3];
            pf.s[4] = pb[0]; pf.s[5] = pb[1]; pf.s[6] = pb[2]; pf.s[7] = pb[3];
#pragma unroll
            for (int dt = 0; dt < 4; ++dt) {
                int row = dt * 16 + r;
                int off = row * 128 + (((ks * 4 + g) ^ (row & 7)) << 4);
                half8 vfrag = *(const half8*)((char*)Vt + off);
                accz[dt] = __builtin_amdgcn_mfma_f32_16x16x32_f16(vfrag, pf.h, accz[dt], 0, 0, 0);
            }
        }
    }

    int src = (r >> 2) << 4;
    float l0 = __shfl(lsum[0], src), l1 = __shfl(lsum[1], src);
    float l2 = __shfl(lsum[2], src), l3 = __shfl(lsum[3], src);
    float lx = (r & 1) ? l1 : l0, ly = (r & 1) ? l3 : l2;
    float inv = 1.0f / ((r & 2) ? ly : lx);
#pragma unroll
    for (int dt = 0; dt < 4; ++dt) {
        ushort4 h4;
#pragma unroll
        for (int e = 0; e < 4; ++e)
            ((unsigned short*)&h4)[e] = f2h(accz[dt][e] * inv);
        size_t off = (qrow0 + wq0 + r) * 512 + n * 64 + dt * 16 + g * 4;
        *(ushort4*)(zh + off) = h4;
    }
}

// ---------------------------------------------------------------------------
// Workspace (bytes, 76 MB total):
//   0   : xh fp16 32M   -> after gemm1: zh fp16 8M (at 0)
//   32M : qk fp16 16M
//   48M : vT fp16 8M
//   56M : wcatT fp16 6M
//   62M : woT fp16 2M
//   64M : wcat fp32 12M (temp, dead after transconv)
// ---------------------------------------------------------------------------
extern "C" void kernel_launch(void* const* d_in, const int* in_sizes, int n_in,
                              void* d_out, int out_size, void* d_ws, size_t ws_size,
                              hipStream_t stream) {
    const float* x  = (const float*)d_in[0];
    const float* wq = (const float*)d_in[1];
    const float* wk = (const float*)d_in[2];
    const float* wv = (const float*)d_in[3];
    const float* wo = (const float*)d_in[4];
    float* out = (float*)d_out;

    char* w = (char*)d_ws;
    unsigned short* xh  = (unsigned short*)(w);
    unsigned short* zh  = (unsigned short*)(w);
    unsigned short* qk  = (unsigned short*)(w + 33554432);
    unsigned short* vT  = (unsigned short*)(w + 50331648);
    unsigned short* wcatT = (unsigned short*)(w + 58720256);
    unsigned short* woT = (unsigned short*)(w + 65011712);
    float*          wcat = (float*)(w + 67108864);

    k_pack<<<dim3((DMODEL * QKV + 255) / 256), 256, 0, stream>>>(wq, wk, wv, wcat);
    k_transconv_h<<<dim3(32, 24), 256, 0, stream>>>(wcat, wcatT, DMODEL, QKV);
    k_transconv_h<<<dim3(8, 32), 256, 0, stream>>>(wo, woT, KVDIM, DMODEL);
    k_convh<<<dim3(16384), 256, 0, stream>>>(x, xh, MROWS * DMODEL / 4);
    k_gemm_qkv<<<dim3(64, 12), 256, 0, stream>>>(xh, wcatT, qk, vT);
    k_attn_mfma<<<dim3(32, NKV, BATCH), 256, 0, stream>>>(qk, vT, zh);
    k_gemm_out<<<dim3(64, 16), 256, 0, stream>>>(zh, woT, out);
}

// Round 9
// 246.133 us; speedup vs baseline: 2.2869x; 1.0192x over previous
//
#include <hip/hip_runtime.h>

typedef __attribute__((ext_vector_type(8))) _Float16 half8;
typedef __attribute__((ext_vector_type(4))) float f32x4;

#define BATCH  4
#define SLEN   2048
#define DMODEL 2048
#define NKV    8
#define GRP    4
#define DH     64
#define QKV    1536
#define KVDIM  512
#define MROWS  (BATCH * SLEN)   // 8192

// ---- fp16 helper (RNE via hardware cvt) ------------------------------------
__device__ __forceinline__ unsigned short f2h(float f) {
    union { _Float16 h; unsigned short u; } cv;
    cv.h = (_Float16)f;
    return cv.u;
}

// ---- async global->LDS, 16B per lane ---------------------------------------
__device__ __forceinline__ void gl16(const void* g, void* l) {
    __builtin_amdgcn_global_load_lds(
        (const __attribute__((address_space(1))) void*)g,
        (__attribute__((address_space(3))) void*)l, 16, 0, 0);
}

typedef __attribute__((ext_vector_type(4))) short short4v;
union U64S4 { unsigned long long u; short4v s; };

// ---------------------------------------------------------------------------
// Kernel 1: pack weights into Wcat[d_model][1536] (fp32).
// ---------------------------------------------------------------------------
__global__ __launch_bounds__(256) void k_pack(const float* __restrict__ wq,
                                              const float* __restrict__ wk,
                                              const float* __restrict__ wv,
                                              float* __restrict__ wcat) {
    int i = blockIdx.x * 256 + threadIdx.x;
    if (i >= DMODEL * QKV) return;
    int d = i / QKV, c = i - d * QKV;
    int mat = c >> 9, rem = c & 511;
    int n = rem >> 6, h = rem & 63;
    float val;
    if (mat == 0) {
        val = 0.0f;
#pragma unroll
        for (int g = 0; g < GRP; ++g)
            val += wq[((size_t)(n * GRP + g) * DMODEL + d) * DH + h];
    } else if (mat == 1) {
        val = wk[((size_t)n * DMODEL + d) * DH + h];
    } else {
        val = wv[((size_t)n * DMODEL + d) * DH + h];
    }
    wcat[(size_t)d * QKV + c] = val;
}

// ---------------------------------------------------------------------------
// Kernel 2: transpose + fp16 convert. in fp32 [R][C] -> fp16 ushort [C][R].
// ---------------------------------------------------------------------------
__global__ __launch_bounds__(256) void k_transconv_h(const float* __restrict__ in,
                                                     unsigned short* __restrict__ outT,
                                                     int R, int C) {
    __shared__ float T[64][65];
    const int r0 = blockIdx.x * 64, c0 = blockIdx.y * 64;
    const int tr = threadIdx.x >> 6, tc = threadIdx.x & 63;
#pragma unroll
    for (int i = 0; i < 16; ++i)
        T[tr + i * 4][tc] = in[(size_t)(r0 + tr + i * 4) * C + c0 + tc];
    __syncthreads();
    const int rr = tc;
#pragma unroll
    for (int i = 0; i < 16; ++i) {
        int cc = tr + i * 4;
        outT[(size_t)(c0 + cc) * R + r0 + rr] = f2h(T[rr][cc]);
    }
}

// ---------------------------------------------------------------------------
// Kernel 3: elementwise fp32 -> fp16.
// ---------------------------------------------------------------------------
__global__ __launch_bounds__(256) void k_convh(const float* __restrict__ in,
                                               unsigned short* __restrict__ out,
                                               int n4) {
    int i = blockIdx.x * 256 + threadIdx.x;
    if (i >= n4) return;
    float4 v = ((const float4*)in)[i];
    ushort4 o;
    o.x = f2h(v.x); o.y = f2h(v.y); o.z = f2h(v.z); o.w = f2h(v.w);
    ((ushort4*)out)[i] = o;
}

// ---------------------------------------------------------------------------
// Plain-fp16 2-phase MFMA GEMM (R5-proven structure) — unchanged from R8.
// ---------------------------------------------------------------------------
__device__ __forceinline__ void stage_tile64(const unsigned short* __restrict__ src,
                                             unsigned short* lds, int t, int K, int k0) {
#pragma unroll
    for (int j = 0; j < 4; ++j) {
        int slot = j * 256 + t;
        int row = slot >> 3, blk = slot & 7;
        int c = blk ^ (row & 7);
        gl16(src + (size_t)row * K + k0 + c * 8, lds + slot * 8);
    }
}

#define GEMMF16_MAIN(Ag, Bg, K_)                                              \
    const int t = threadIdx.x;                                                \
    const size_t m0 = (size_t)blockIdx.x * 128, n0 = (size_t)blockIdx.y * 128;\
    const int w = t >> 6, l = t & 63;                                         \
    const int wm = (w >> 1) * 64, wn = (w & 1) * 64;                          \
    const int r = l & 15, q = l >> 4;                                         \
    f32x4 acc[4][4] = {};                                                     \
    const int K = (K_);                                                       \
    const int NT = K / 64;                                                    \
    stage_tile64(Ag + m0 * K, A2[0], t, K, 0);                                \
    stage_tile64(Bg + n0 * K, B2[0], t, K, 0);                                \
    asm volatile("s_waitcnt vmcnt(0)" ::: "memory");                          \
    __builtin_amdgcn_s_barrier();                                             \
    int cur = 0;                                                              \
    for (int kt = 0; kt < NT; ++kt) {                                         \
        if (kt + 1 < NT) {                                                    \
            stage_tile64(Ag + m0 * K, A2[cur ^ 1], t, K, (kt + 1) * 64);      \
            stage_tile64(Bg + n0 * K, B2[cur ^ 1], t, K, (kt + 1) * 64);      \
        }                                                                     \
        const unsigned short* Ac = A2[cur];                                   \
        const unsigned short* Bc = B2[cur];                                   \
        half8 af[4][2], bf[4][2];                                             \
        _Pragma("unroll") for (int i = 0; i < 4; ++i)                         \
            _Pragma("unroll") for (int ks = 0; ks < 2; ++ks) {                \
                int ra = wm + i * 16 + r;                                     \
                af[i][ks] = *(const half8*)&Ac[ra * 64 +                      \
                    ((((ks << 2) | q) ^ (ra & 7)) << 3)];                     \
                int rb = wn + i * 16 + r;                                     \
                bf[i][ks] = *(const half8*)&Bc[rb * 64 +                      \
                    ((((ks << 2) | q) ^ (rb & 7)) << 3)];                     \
            }                                                                 \
        __builtin_amdgcn_s_setprio(1);                                        \
        _Pragma("unroll") for (int i = 0; i < 4; ++i)                         \
            _Pragma("unroll") for (int j = 0; j < 4; ++j) {                   \
                acc[i][j] = __builtin_amdgcn_mfma_f32_16x16x32_f16(           \
                    af[i][0], bf[j][0], acc[i][j], 0, 0, 0);                  \
                acc[i][j] = __builtin_amdgcn_mfma_f32_16x16x32_f16(           \
                    af[i][1], bf[j][1], acc[i][j], 0, 0, 0);                  \
            }                                                                 \
        __builtin_amdgcn_s_setprio(0);                                        \
        asm volatile("s_waitcnt vmcnt(0)" ::: "memory");                      \
        __builtin_amdgcn_s_barrier();                                         \
        cur ^= 1;                                                             \
    }

// ---------------------------------------------------------------------------
// Kernel 4: fp16 GEMM -> QKV (unchanged from R8).
// ---------------------------------------------------------------------------
__global__ __launch_bounds__(256) void k_gemm_qkv(
        const unsigned short* __restrict__ Ag, const unsigned short* __restrict__ Bg,
        unsigned short* __restrict__ qk, unsigned short* __restrict__ vT) {
    __shared__ unsigned short A2[2][128 * 64];
    __shared__ unsigned short B2[2][128 * 64];

    GEMMF16_MAIN(Ag, Bg, DMODEL)

    if (n0 < 1024) {
#pragma unroll
        for (int i = 0; i < 4; ++i)
#pragma unroll
            for (int j = 0; j < 4; ++j) {
                int col = (int)n0 + wn + j * 16 + r;
                size_t rowb = m0 + wm + i * 16 + q * 4;
#pragma unroll
                for (int e = 0; e < 4; ++e)
                    qk[(rowb + e) * 1024 + col] = f2h(acc[i][j][e]);
            }
    } else {
#pragma unroll
        for (int i = 0; i < 4; ++i)
#pragma unroll
            for (int j = 0; j < 4; ++j) {
                int d = (int)n0 - 1024 + wn + j * 16 + r;
                size_t rowb = m0 + wm + i * 16 + q * 4;
                ushort4 pk;
                pk.x = f2h(acc[i][j][0]); pk.y = f2h(acc[i][j][1]);
                pk.z = f2h(acc[i][j][2]); pk.w = f2h(acc[i][j][3]);
                *(ushort4*)&vT[(size_t)d * MROWS + rowb] = pk;
            }
    }
}

// ---------------------------------------------------------------------------
// Kernel 6: fp16 GEMM, fp32 C (output projection) — unchanged from R8.
// ---------------------------------------------------------------------------
__global__ __launch_bounds__(256) void k_gemm_out(
        const unsigned short* __restrict__ Ag, const unsigned short* __restrict__ Bg,
        float* __restrict__ C) {
    __shared__ unsigned short A2[2][128 * 64];
    __shared__ unsigned short B2[2][128 * 64];

    GEMMF16_MAIN(Ag, Bg, KVDIM)

#pragma unroll
    for (int i = 0; i < 4; ++i)
#pragma unroll
        for (int j = 0; j < 4; ++j) {
            int col = (int)n0 + wn + j * 16 + r;
            size_t rowb = m0 + wm + i * 16 + q * 4;
#pragma unroll
            for (int e = 0; e < 4; ++e)
                C[(rowb + e) * DMODEL + col] = acc[i][j][e];
        }
}

// ---------------------------------------------------------------------------
// Kernel 5: fp16 MFMA flash attention, R9 upgrades:
//  - async double-buffered K/V staging via global_load_lds with pre-swizzled
//    source (issue for kt+1 at top of kt, vmcnt(0) drain at bottom) — removes
//    the per-tile exposed global latency that capped MfmaUtil at 5.7%.
//  - Q pre-scaled by 0.125 (exact in fp16); mask only on diagonal tile.
//  - defer-max (T13, THR=8): skip alpha broadcast + accz rescale when
//    __all(pmax - m <= 8); P bounded by e^8 (fits fp16), lsum/accz fp32.
// LDS: Ks 16KB + Vs 16KB + Pt 8KB = 40KB -> 4 blocks/CU.
// ---------------------------------------------------------------------------
__global__ __launch_bounds__(256) void k_attn_mfma(
        const unsigned short* __restrict__ qk, const unsigned short* __restrict__ vT,
        unsigned short* __restrict__ zh) {
    __shared__ unsigned short Ks[2][64 * 64];
    __shared__ unsigned short Vs[2][64 * 64];
    __shared__ unsigned short Pt[4 * 64 * 16];   // per-wave 2KB

    const int t  = threadIdx.x;
    const int w  = t >> 6, l = t & 63;
    const int qt = 31 - blockIdx.x;   // big tiles first
    const int n  = blockIdx.y, b = blockIdx.z;
    const int r  = l & 15, g = l >> 4;
    const int wq0 = w * 16;
    const size_t qrow0 = (size_t)(b * SLEN + qt * 64);

    // staging geometry: 2 slots/thread/matrix; dest linear, source inverse-swz
    const int s0 = t, s1 = 256 + t;
    const int row0 = s0 >> 3, c0b = (s0 & 7) ^ (row0 & 7);
    const int row1 = s1 >> 3, c1b = (s1 & 7) ^ (row1 & 7);

#define STAGE_KV(buf, kr0)                                                    \
    gl16(qk + ((kr0) + row0) * 1024 + 512 + n * 64 + c0b * 8, &Ks[buf][s0 * 8]); \
    gl16(qk + ((kr0) + row1) * 1024 + 512 + n * 64 + c1b * 8, &Ks[buf][s1 * 8]); \
    gl16(vT + (size_t)(n * 64 + row0) * MROWS + (kr0) + c0b * 8, &Vs[buf][s0 * 8]); \
    gl16(vT + (size_t)(n * 64 + row1) * MROWS + (kr0) + c1b * 8, &Vs[buf][s1 * 8]);

    // Q fragments, pre-scaled by 0.125 (exact power of two in fp16)
    half8 qh[2];
#pragma unroll
    for (int ks = 0; ks < 2; ++ks) {
        size_t off = (qrow0 + wq0 + r) * 1024 + n * 64 + ks * 32 + g * 8;
        qh[ks] = *(const half8*)(qk + off);
#pragma unroll
        for (int e2 = 0; e2 < 8; ++e2) qh[ks][e2] = qh[ks][e2] * (_Float16)0.125f;
    }

    STAGE_KV(0, (size_t)(b * SLEN))
    asm volatile("s_waitcnt vmcnt(0)" ::: "memory");
    __builtin_amdgcn_s_barrier();

    float m_[4], lsum[4];
#pragma unroll
    for (int e = 0; e < 4; ++e) { m_[e] = -3.0e38f; lsum[e] = 0.0f; }
    f32x4 accz[4] = {};

    for (int kt = 0; kt <= qt; ++kt) {
        const int cur = kt & 1;
        if (kt < qt) {
            STAGE_KV(cur ^ 1, (size_t)(b * SLEN + (kt + 1) * 64))
        }
        const unsigned short* Ksc = Ks[cur];
        const unsigned short* Vsc = Vs[cur];

        // S = (Q/8).K^T
        f32x4 s[4] = {};
#pragma unroll
        for (int ct = 0; ct < 4; ++ct)
#pragma unroll
            for (int ks = 0; ks < 2; ++ks) {
                int row = ct * 16 + r;
                int off = row * 128 + (((ks * 4 + g) ^ (row & 7)) << 4);
                half8 kh8 = *(const half8*)((char*)Ksc + off);
                s[ct] = __builtin_amdgcn_mfma_f32_16x16x32_f16(qh[ks], kh8, s[ct], 0, 0, 0);
            }

        // causal mask: only the diagonal tile (wave-uniform branch)
        if (kt == qt) {
#pragma unroll
            for (int ct = 0; ct < 4; ++ct)
#pragma unroll
                for (int e = 0; e < 4; ++e)
                    if ((ct * 16 + r) > (wq0 + g * 4 + e))
                        s[ct][e] = -100000.0f;   // reference IGNORE
        }

        // row max (rows wq0+g*4+e live across 16-lane r-group)
        float pm[4];
#pragma unroll
        for (int e = 0; e < 4; ++e) {
            float p = fmaxf(fmaxf(s[0][e], s[1][e]), fmaxf(s[2][e], s[3][e]));
            p = fmaxf(p, __shfl_xor(p, 1));
            p = fmaxf(p, __shfl_xor(p, 2));
            p = fmaxf(p, __shfl_xor(p, 4));
            p = fmaxf(p, __shfl_xor(p, 8));
            pm[e] = p;
        }

        // defer-max: rescale only if some row grew by > 8
        float al[4] = {1.0f, 1.0f, 1.0f, 1.0f};
        float dm = fmaxf(fmaxf(pm[0] - m_[0], pm[1] - m_[1]),
                         fmaxf(pm[2] - m_[2], pm[3] - m_[3]));
        if (!__all(dm <= 8.0f)) {
#pragma unroll
            for (int e = 0; e < 4; ++e) {
                float nm = fmaxf(m_[e], pm[e]);
                al[e] = __expf(m_[e] - nm);
                m_[e] = nm;
            }
            int src = (r >> 2) << 4;
            float a0 = __shfl(al[0], src), a1 = __shfl(al[1], src);
            float a2 = __shfl(al[2], src), a3 = __shfl(al[3], src);
            float ax = (r & 1) ? a1 : a0, ay = (r & 1) ? a3 : a2;
            float aq = (r & 2) ? ay : ax;
#pragma unroll
            for (int dt = 0; dt < 4; ++dt) {
                accz[dt][0] *= aq; accz[dt][1] *= aq;
                accz[dt][2] *= aq; accz[dt][3] *= aq;
            }
        }

        // P = exp(S - m), pack fp16, write P^T (row-permuted) to per-wave LDS
        float ps[4] = {};
#pragma unroll
        for (int ct = 0; ct < 4; ++ct) {
            float p0 = __expf(s[ct][0] - m_[0]);
            float p1 = __expf(s[ct][1] - m_[1]);
            float p2 = __expf(s[ct][2] - m_[2]);
            float p3 = __expf(s[ct][3] - m_[3]);
            ps[0] += p0; ps[1] += p1; ps[2] += p2; ps[3] += p3;
            short4v pk = { (short)f2h(p0), (short)f2h(p1),
                           (short)f2h(p2), (short)f2h(p3) };
            int kv = ct * 16 + r;
            int phys = (kv >> 5) * 32 + (((kv >> 2) & 1) << 4)
                     + (((kv >> 3) & 3) << 2) + (kv & 3);
            *(short4v*)((char*)Pt + w * 2048 + phys * 32 + g * 8) = pk;
        }

#pragma unroll
        for (int e = 0; e < 4; ++e) {
            float rs = ps[e];
            rs += __shfl_xor(rs, 1); rs += __shfl_xor(rs, 2);
            rs += __shfl_xor(rs, 4); rs += __shfl_xor(rs, 8);
            lsum[e] = lsum[e] * al[e] + rs;
        }

        // PV: z^T += V^T . P^T  (wave-private Pt; drain writes, tr-read)
        asm volatile("s_waitcnt lgkmcnt(0)" ::: "memory");
        __builtin_amdgcn_sched_barrier(0);
#pragma unroll
        for (int ks = 0; ks < 2; ++ks) {
            unsigned base = (unsigned)(size_t)((char*)Pt + w * 2048 + ks * 1024) + l * 8;
            U64S4 t1, t2;
            asm volatile("ds_read_b64_tr_b16 %0, %1" : "=v"(t1.u) : "v"(base) : "memory");
            asm volatile("ds_read_b64_tr_b16 %0, %1" : "=v"(t2.u) : "v"(base + 512) : "memory");
            asm volatile("s_waitcnt lgkmcnt(0)" ::: "memory");
            __builtin_amdgcn_sched_barrier(0);
            short4v pa = t1.s, pb = t2.s;
            union { short s[8]; half8 h; } pf;
            pf.s[0] = pa[0]; pf.s[1] = pa[1]; pf.s[2] = pa[2]; pf.s[3] = pa[3];
            pf.s[4] = pb[0]; pf.s[5] = pb[1]; pf.s[6] = pb[2]; pf.s[7] = pb[3];
#pragma unroll
            for (int dt = 0; dt < 4; ++dt) {
                int row = dt * 16 + r;
                int off = row * 128 + (((ks * 4 + g) ^ (row & 7)) << 4);
                half8 vfrag = *(const half8*)((char*)Vsc + off);
                accz[dt] = __builtin_amdgcn_mfma_f32_16x16x32_f16(vfrag, pf.h, accz[dt], 0, 0, 0);
            }
        }

        asm volatile("s_waitcnt vmcnt(0)" ::: "memory");   // next tile staged
        __builtin_amdgcn_s_barrier();
    }

    int src = (r >> 2) << 4;
    float l0 = __shfl(lsum[0], src), l1 = __shfl(lsum[1], src);
    float l2 = __shfl(lsum[2], src), l3 = __shfl(lsum[3], src);
    float lx = (r & 1) ? l1 : l0, ly = (r & 1) ? l3 : l2;
    float inv = 1.0f / ((r & 2) ? ly : lx);
#pragma unroll
    for (int dt = 0; dt < 4; ++dt) {
        ushort4 h4;
#pragma unroll
        for (int e = 0; e < 4; ++e)
            ((unsigned short*)&h4)[e] = f2h(accz[dt][e] * inv);
        size_t off = (qrow0 + wq0 + r) * 512 + n * 64 + dt * 16 + g * 4;
        *(ushort4*)(zh + off) = h4;
    }
#undef STAGE_KV
}

// ---------------------------------------------------------------------------
// Workspace (bytes, 76 MB total):
//   0   : xh fp16 32M   -> after gemm1: zh fp16 8M (at 0)
//   32M : qk fp16 16M
//   48M : vT fp16 8M
//   56M : wcatT fp16 6M
//   62M : woT fp16 2M
//   64M : wcat fp32 12M (temp, dead after transconv)
// ---------------------------------------------------------------------------
extern "C" void kernel_launch(void* const* d_in, const int* in_sizes, int n_in,
                              void* d_out, int out_size, void* d_ws, size_t ws_size,
                              hipStream_t stream) {
    const float* x  = (const float*)d_in[0];
    const float* wq = (const float*)d_in[1];
    const float* wk = (const float*)d_in[2];
    const float* wv = (const float*)d_in[3];
    const float* wo = (const float*)d_in[4];
    float* out = (float*)d_out;

    char* w = (char*)d_ws;
    unsigned short* xh  = (unsigned short*)(w);
    unsigned short* zh  = (unsigned short*)(w);
    unsigned short* qk  = (unsigned short*)(w + 33554432);
    unsigned short* vT  = (unsigned short*)(w + 50331648);
    unsigned short* wcatT = (unsigned short*)(w + 58720256);
    unsigned short* woT = (unsigned short*)(w + 65011712);
    float*          wcat = (float*)(w + 67108864);

    k_pack<<<dim3((DMODEL * QKV + 255) / 256), 256, 0, stream>>>(wq, wk, wv, wcat);
    k_transconv_h<<<dim3(32, 24), 256, 0, stream>>>(wcat, wcatT, DMODEL, QKV);
    k_transconv_h<<<dim3(8, 32), 256, 0, stream>>>(wo, woT, KVDIM, DMODEL);
    k_convh<<<dim3(16384), 256, 0, stream>>>(x, xh, MROWS * DMODEL / 4);
    k_gemm_qkv<<<dim3(64, 12), 256, 0, stream>>>(xh, wcatT, qk, vT);
    k_attn_mfma<<<dim3(32, NKV, BATCH), 256, 0, stream>>>(qk, vT, zh);
    k_gemm_out<<<dim3(64, 16), 256, 0, stream>>>(zh, woT, out);
}

// Round 10
// 215.637 us; speedup vs baseline: 2.6104x; 1.1414x over previous
//
#include <hip/hip_runtime.h>

typedef __attribute__((ext_vector_type(8))) _Float16 half8;
typedef __attribute__((ext_vector_type(4))) float f32x4;

#define BATCH  4
#define SLEN   2048
#define DMODEL 2048
#define NKV    8
#define GRP    4
#define DH     64
#define QKV    1536
#define KVDIM  512
#define MROWS  (BATCH * SLEN)   // 8192

// ---- fp16 helper (RNE via hardware cvt) ------------------------------------
__device__ __forceinline__ unsigned short f2h(float f) {
    union { _Float16 h; unsigned short u; } cv;
    cv.h = (_Float16)f;
    return cv.u;
}

// ---- async global->LDS, 16B per lane ---------------------------------------
__device__ __forceinline__ void gl16(const void* g, void* l) {
    __builtin_amdgcn_global_load_lds(
        (const __attribute__((address_space(1))) void*)g,
        (__attribute__((address_space(3))) void*)l, 16, 0, 0);
}

typedef __attribute__((ext_vector_type(4))) short short4v;
union U64S4 { unsigned long long u; short4v s; };

// ---------------------------------------------------------------------------
// Kernel 1: pack weights into Wcat[d_model][1536] (fp32).
// ---------------------------------------------------------------------------
__global__ __launch_bounds__(256) void k_pack(const float* __restrict__ wq,
                                              const float* __restrict__ wk,
                                              const float* __restrict__ wv,
                                              float* __restrict__ wcat) {
    int i = blockIdx.x * 256 + threadIdx.x;
    if (i >= DMODEL * QKV) return;
    int d = i / QKV, c = i - d * QKV;
    int mat = c >> 9, rem = c & 511;
    int n = rem >> 6, h = rem & 63;
    float val;
    if (mat == 0) {
        val = 0.0f;
#pragma unroll
        for (int g = 0; g < GRP; ++g)
            val += wq[((size_t)(n * GRP + g) * DMODEL + d) * DH + h];
    } else if (mat == 1) {
        val = wk[((size_t)n * DMODEL + d) * DH + h];
    } else {
        val = wv[((size_t)n * DMODEL + d) * DH + h];
    }
    wcat[(size_t)d * QKV + c] = val;
}

// ---------------------------------------------------------------------------
// Kernel 2: transpose + fp16 convert. in fp32 [R][C] -> fp16 ushort [C][R].
// ---------------------------------------------------------------------------
__global__ __launch_bounds__(256) void k_transconv_h(const float* __restrict__ in,
                                                     unsigned short* __restrict__ outT,
                                                     int R, int C) {
    __shared__ float T[64][65];
    const int r0 = blockIdx.x * 64, c0 = blockIdx.y * 64;
    const int tr = threadIdx.x >> 6, tc = threadIdx.x & 63;
#pragma unroll
    for (int i = 0; i < 16; ++i)
        T[tr + i * 4][tc] = in[(size_t)(r0 + tr + i * 4) * C + c0 + tc];
    __syncthreads();
    const int rr = tc;
#pragma unroll
    for (int i = 0; i < 16; ++i) {
        int cc = tr + i * 4;
        outT[(size_t)(c0 + cc) * R + r0 + rr] = f2h(T[rr][cc]);
    }
}

// ---------------------------------------------------------------------------
// Kernel 3: elementwise fp32 -> fp16.
// ---------------------------------------------------------------------------
__global__ __launch_bounds__(256) void k_convh(const float* __restrict__ in,
                                               unsigned short* __restrict__ out,
                                               int n4) {
    int i = blockIdx.x * 256 + threadIdx.x;
    if (i >= n4) return;
    float4 v = ((const float4*)in)[i];
    ushort4 o;
    o.x = f2h(v.x); o.y = f2h(v.y); o.z = f2h(v.z); o.w = f2h(v.w);
    ((ushort4*)out)[i] = o;
}

// ---------------------------------------------------------------------------
// Plain-fp16 2-phase MFMA GEMM (R5-proven structure) — unchanged from R8.
// ---------------------------------------------------------------------------
__device__ __forceinline__ void stage_tile64(const unsigned short* __restrict__ src,
                                             unsigned short* lds, int t, int K, int k0) {
#pragma unroll
    for (int j = 0; j < 4; ++j) {
        int slot = j * 256 + t;
        int row = slot >> 3, blk = slot & 7;
        int c = blk ^ (row & 7);
        gl16(src + (size_t)row * K + k0 + c * 8, lds + slot * 8);
    }
}

#define GEMMF16_MAIN(Ag, Bg, K_)                                              \
    const int t = threadIdx.x;                                                \
    const size_t m0 = (size_t)blockIdx.x * 128, n0 = (size_t)blockIdx.y * 128;\
    const int w = t >> 6, l = t & 63;                                         \
    const int wm = (w >> 1) * 64, wn = (w & 1) * 64;                          \
    const int r = l & 15, q = l >> 4;                                         \
    f32x4 acc[4][4] = {};                                                     \
    const int K = (K_);                                                       \
    const int NT = K / 64;                                                    \
    stage_tile64(Ag + m0 * K, A2[0], t, K, 0);                                \
    stage_tile64(Bg + n0 * K, B2[0], t, K, 0);                                \
    asm volatile("s_waitcnt vmcnt(0)" ::: "memory");                          \
    __builtin_amdgcn_s_barrier();                                             \
    int cur = 0;                                                              \
    for (int kt = 0; kt < NT; ++kt) {                                         \
        if (kt + 1 < NT) {                                                    \
            stage_tile64(Ag + m0 * K, A2[cur ^ 1], t, K, (kt + 1) * 64);      \
            stage_tile64(Bg + n0 * K, B2[cur ^ 1], t, K, (kt + 1) * 64);      \
        }                                                                     \
        const unsigned short* Ac = A2[cur];                                   \
        const unsigned short* Bc = B2[cur];                                   \
        half8 af[4][2], bf[4][2];                                             \
        _Pragma("unroll") for (int i = 0; i < 4; ++i)                         \
            _Pragma("unroll") for (int ks = 0; ks < 2; ++ks) {                \
                int ra = wm + i * 16 + r;                                     \
                af[i][ks] = *(const half8*)&Ac[ra * 64 +                      \
                    ((((ks << 2) | q) ^ (ra & 7)) << 3)];                     \
                int rb = wn + i * 16 + r;                                     \
                bf[i][ks] = *(const half8*)&Bc[rb * 64 +                      \
                    ((((ks << 2) | q) ^ (rb & 7)) << 3)];                     \
            }                                                                 \
        __builtin_amdgcn_s_setprio(1);                                        \
        _Pragma("unroll") for (int i = 0; i < 4; ++i)                         \
            _Pragma("unroll") for (int j = 0; j < 4; ++j) {                   \
                acc[i][j] = __builtin_amdgcn_mfma_f32_16x16x32_f16(           \
                    af[i][0], bf[j][0], acc[i][j], 0, 0, 0);                  \
                acc[i][j] = __builtin_amdgcn_mfma_f32_16x16x32_f16(           \
                    af[i][1], bf[j][1], acc[i][j], 0, 0, 0);                  \
            }                                                                 \
        __builtin_amdgcn_s_setprio(0);                                        \
        asm volatile("s_waitcnt vmcnt(0)" ::: "memory");                      \
        __builtin_amdgcn_s_barrier();                                         \
        cur ^= 1;                                                             \
    }

// ---------------------------------------------------------------------------
// Kernel 4: fp16 GEMM -> QKV (unchanged from R8).
// ---------------------------------------------------------------------------
__global__ __launch_bounds__(256) void k_gemm_qkv(
        const unsigned short* __restrict__ Ag, const unsigned short* __restrict__ Bg,
        unsigned short* __restrict__ qk, unsigned short* __restrict__ vT) {
    __shared__ unsigned short A2[2][128 * 64];
    __shared__ unsigned short B2[2][128 * 64];

    GEMMF16_MAIN(Ag, Bg, DMODEL)

    if (n0 < 1024) {
#pragma unroll
        for (int i = 0; i < 4; ++i)
#pragma unroll
            for (int j = 0; j < 4; ++j) {
                int col = (int)n0 + wn + j * 16 + r;
                size_t rowb = m0 + wm + i * 16 + q * 4;
#pragma unroll
                for (int e = 0; e < 4; ++e)
                    qk[(rowb + e) * 1024 + col] = f2h(acc[i][j][e]);
            }
    } else {
#pragma unroll
        for (int i = 0; i < 4; ++i)
#pragma unroll
            for (int j = 0; j < 4; ++j) {
                int d = (int)n0 - 1024 + wn + j * 16 + r;
                size_t rowb = m0 + wm + i * 16 + q * 4;
                ushort4 pk;
                pk.x = f2h(acc[i][j][0]); pk.y = f2h(acc[i][j][1]);
                pk.z = f2h(acc[i][j][2]); pk.w = f2h(acc[i][j][3]);
                *(ushort4*)&vT[(size_t)d * MROWS + rowb] = pk;
            }
    }
}

// ---------------------------------------------------------------------------
// Kernel 6: fp16 GEMM, fp32 C (output projection) — unchanged from R8.
// ---------------------------------------------------------------------------
__global__ __launch_bounds__(256) void k_gemm_out(
        const unsigned short* __restrict__ Ag, const unsigned short* __restrict__ Bg,
        float* __restrict__ C) {
    __shared__ unsigned short A2[2][128 * 64];
    __shared__ unsigned short B2[2][128 * 64];

    GEMMF16_MAIN(Ag, Bg, KVDIM)

#pragma unroll
    for (int i = 0; i < 4; ++i)
#pragma unroll
        for (int j = 0; j < 4; ++j) {
            int col = (int)n0 + wn + j * 16 + r;
            size_t rowb = m0 + wm + i * 16 + q * 4;
#pragma unroll
            for (int e = 0; e < 4; ++e)
                C[(rowb + e) * DMODEL + col] = acc[i][j][e];
        }
}

// ---------------------------------------------------------------------------
// Kernel 5: fp16 MFMA flash attention.  R10 changes:
//  - COMPLEMENTARY Q-TILE PAIRING: block p handles q-tiles (31-p) then (p)
//    sequentially -> every block does exactly 33 k-tiles; 512 blocks = 2/CU
//    with uniform work (fixes the 2x critical-path imbalance seen in R9:
//    co-resident blocks shared the same qt, Occupancy 19%, MfmaUtil 6%).
//  - defer-max REVERTED (R9 absmax regression 0.0078 -> 0.0277): always
//    rescale with the new running max.
//  - keeps R9's async double-buffered K/V staging (gl16, pre-swizzled src)
//    and Q pre-scaled by 0.125.
// LDS: Ks 16KB + Vs 16KB + Pt 8KB = 40KB.
// ---------------------------------------------------------------------------
__global__ __launch_bounds__(256) void k_attn_mfma(
        const unsigned short* __restrict__ qk, const unsigned short* __restrict__ vT,
        unsigned short* __restrict__ zh) {
    __shared__ unsigned short Ks[2][64 * 64];
    __shared__ unsigned short Vs[2][64 * 64];
    __shared__ unsigned short Pt[4 * 64 * 16];   // per-wave 2KB

    const int t  = threadIdx.x;
    const int w  = t >> 6, l = t & 63;
    const int p  = blockIdx.x;        // 0..15 (pair index)
    const int n  = blockIdx.y, b = blockIdx.z;
    const int r  = l & 15, g = l >> 4;
    const int wq0 = w * 16;

    // staging geometry: 2 slots/thread/matrix; dest linear, source inverse-swz
    const int s0 = t, s1 = 256 + t;
    const int row0 = s0 >> 3, c0b = (s0 & 7) ^ (row0 & 7);
    const int row1 = s1 >> 3, c1b = (s1 & 7) ^ (row1 & 7);

#define STAGE_KV(buf, kr0)                                                    \
    gl16(qk + ((kr0) + row0) * 1024 + 512 + n * 64 + c0b * 8, &Ks[buf][s0 * 8]); \
    gl16(qk + ((kr0) + row1) * 1024 + 512 + n * 64 + c1b * 8, &Ks[buf][s1 * 8]); \
    gl16(vT + (size_t)(n * 64 + row0) * MROWS + (kr0) + c0b * 8, &Vs[buf][s0 * 8]); \
    gl16(vT + (size_t)(n * 64 + row1) * MROWS + (kr0) + c1b * 8, &Vs[buf][s1 * 8]);

#pragma unroll 1
    for (int seg = 0; seg < 2; ++seg) {
        const int qt = seg ? p : (31 - p);   // heavy tile first
        const size_t qrow0 = (size_t)(b * SLEN + qt * 64);

        // Q fragments, pre-scaled by 0.125 (exact power of two in fp16)
        half8 qh[2];
#pragma unroll
        for (int ks = 0; ks < 2; ++ks) {
            size_t off = (qrow0 + wq0 + r) * 1024 + n * 64 + ks * 32 + g * 8;
            qh[ks] = *(const half8*)(qk + off);
#pragma unroll
            for (int e2 = 0; e2 < 8; ++e2) qh[ks][e2] = qh[ks][e2] * (_Float16)0.125f;
        }

        STAGE_KV(0, (size_t)(b * SLEN))
        asm volatile("s_waitcnt vmcnt(0)" ::: "memory");
        __builtin_amdgcn_s_barrier();

        float m_[4], lsum[4];
#pragma unroll
        for (int e = 0; e < 4; ++e) { m_[e] = -3.0e38f; lsum[e] = 0.0f; }
        f32x4 accz[4] = {};

        for (int kt = 0; kt <= qt; ++kt) {
            const int cur = kt & 1;
            if (kt < qt) {
                STAGE_KV(cur ^ 1, (size_t)(b * SLEN + (kt + 1) * 64))
            }
            const unsigned short* Ksc = Ks[cur];
            const unsigned short* Vsc = Vs[cur];

            // S = (Q/8).K^T
            f32x4 s[4] = {};
#pragma unroll
            for (int ct = 0; ct < 4; ++ct)
#pragma unroll
                for (int ks = 0; ks < 2; ++ks) {
                    int row = ct * 16 + r;
                    int off = row * 128 + (((ks * 4 + g) ^ (row & 7)) << 4);
                    half8 kh8 = *(const half8*)((char*)Ksc + off);
                    s[ct] = __builtin_amdgcn_mfma_f32_16x16x32_f16(qh[ks], kh8, s[ct], 0, 0, 0);
                }

            // causal mask: only the diagonal tile (wave-uniform branch)
            if (kt == qt) {
#pragma unroll
                for (int ct = 0; ct < 4; ++ct)
#pragma unroll
                    for (int e = 0; e < 4; ++e)
                        if ((ct * 16 + r) > (wq0 + g * 4 + e))
                            s[ct][e] = -100000.0f;   // reference IGNORE
            }

            // online softmax: row max + rescale (rows wq0+g*4+e on r-group)
            float al[4], nm[4];
#pragma unroll
            for (int e = 0; e < 4; ++e) {
                float pm = fmaxf(fmaxf(s[0][e], s[1][e]), fmaxf(s[2][e], s[3][e]));
                pm = fmaxf(pm, __shfl_xor(pm, 1));
                pm = fmaxf(pm, __shfl_xor(pm, 2));
                pm = fmaxf(pm, __shfl_xor(pm, 4));
                pm = fmaxf(pm, __shfl_xor(pm, 8));
                nm[e] = fmaxf(m_[e], pm);
                al[e] = __expf(m_[e] - nm[e]);
                m_[e] = nm[e];
            }
            {
                int src = (r >> 2) << 4;
                float a0 = __shfl(al[0], src), a1 = __shfl(al[1], src);
                float a2 = __shfl(al[2], src), a3 = __shfl(al[3], src);
                float ax = (r & 1) ? a1 : a0, ay = (r & 1) ? a3 : a2;
                float aq = (r & 2) ? ay : ax;
#pragma unroll
                for (int dt = 0; dt < 4; ++dt) {
                    accz[dt][0] *= aq; accz[dt][1] *= aq;
                    accz[dt][2] *= aq; accz[dt][3] *= aq;
                }
            }

            // P = exp(S - m), pack fp16, write P^T (row-permuted) to LDS
            float ps[4] = {};
#pragma unroll
            for (int ct = 0; ct < 4; ++ct) {
                float p0 = __expf(s[ct][0] - m_[0]);
                float p1 = __expf(s[ct][1] - m_[1]);
                float p2 = __expf(s[ct][2] - m_[2]);
                float p3 = __expf(s[ct][3] - m_[3]);
                ps[0] += p0; ps[1] += p1; ps[2] += p2; ps[3] += p3;
                short4v pk = { (short)f2h(p0), (short)f2h(p1),
                               (short)f2h(p2), (short)f2h(p3) };
                int kv = ct * 16 + r;
                int phys = (kv >> 5) * 32 + (((kv >> 2) & 1) << 4)
                         + (((kv >> 3) & 3) << 2) + (kv & 3);
                *(short4v*)((char*)Pt + w * 2048 + phys * 32 + g * 8) = pk;
            }

#pragma unroll
            for (int e = 0; e < 4; ++e) {
                float rs = ps[e];
                rs += __shfl_xor(rs, 1); rs += __shfl_xor(rs, 2);
                rs += __shfl_xor(rs, 4); rs += __shfl_xor(rs, 8);
                lsum[e] = lsum[e] * al[e] + rs;
            }

            // PV: z^T += V^T . P^T  (wave-private Pt; drain writes, tr-read)
            asm volatile("s_waitcnt lgkmcnt(0)" ::: "memory");
            __builtin_amdgcn_sched_barrier(0);
#pragma unroll
            for (int ks = 0; ks < 2; ++ks) {
                unsigned base = (unsigned)(size_t)((char*)Pt + w * 2048 + ks * 1024) + l * 8;
                U64S4 t1, t2;
                asm volatile("ds_read_b64_tr_b16 %0, %1" : "=v"(t1.u) : "v"(base) : "memory");
                asm volatile("ds_read_b64_tr_b16 %0, %1" : "=v"(t2.u) : "v"(base + 512) : "memory");
                asm volatile("s_waitcnt lgkmcnt(0)" ::: "memory");
                __builtin_amdgcn_sched_barrier(0);
                short4v pa = t1.s, pb = t2.s;
                union { short s[8]; half8 h; } pf;
                pf.s[0] = pa[0]; pf.s[1] = pa[1]; pf.s[2] = pa[2]; pf.s[3] = pa[3];
                pf.s[4] = pb[0]; pf.s[5] = pb[1]; pf.s[6] = pb[2]; pf.s[7] = pb[3];
#pragma unroll
                for (int dt = 0; dt < 4; ++dt) {
                    int row = dt * 16 + r;
                    int off = row * 128 + (((ks * 4 + g) ^ (row & 7)) << 4);
                    half8 vfrag = *(const half8*)((char*)Vsc + off);
                    accz[dt] = __builtin_amdgcn_mfma_f32_16x16x32_f16(vfrag, pf.h, accz[dt], 0, 0, 0);
                }
            }

            asm volatile("s_waitcnt vmcnt(0)" ::: "memory");   // next tile staged
            __builtin_amdgcn_s_barrier();
        }

        // normalize (1/l for this lane's accumulator column q=r), write z
        int src = (r >> 2) << 4;
        float l0 = __shfl(lsum[0], src), l1 = __shfl(lsum[1], src);
        float l2 = __shfl(lsum[2], src), l3 = __shfl(lsum[3], src);
        float lx = (r & 1) ? l1 : l0, ly = (r & 1) ? l3 : l2;
        float inv = 1.0f / ((r & 2) ? ly : lx);
#pragma unroll
        for (int dt = 0; dt < 4; ++dt) {
            ushort4 h4;
#pragma unroll
            for (int e = 0; e < 4; ++e)
                ((unsigned short*)&h4)[e] = f2h(accz[dt][e] * inv);
            size_t off = (qrow0 + wq0 + r) * 512 + n * 64 + dt * 16 + g * 4;
            *(ushort4*)(zh + off) = h4;
        }
    }
#undef STAGE_KV
}

// ---------------------------------------------------------------------------
// Workspace (bytes, 76 MB total):
//   0   : xh fp16 32M   -> after gemm1: zh fp16 8M (at 0)
//   32M : qk fp16 16M
//   48M : vT fp16 8M
//   56M : wcatT fp16 6M
//   62M : woT fp16 2M
//   64M : wcat fp32 12M (temp, dead after transconv)
// ---------------------------------------------------------------------------
extern "C" void kernel_launch(void* const* d_in, const int* in_sizes, int n_in,
                              void* d_out, int out_size, void* d_ws, size_t ws_size,
                              hipStream_t stream) {
    const float* x  = (const float*)d_in[0];
    const float* wq = (const float*)d_in[1];
    const float* wk = (const float*)d_in[2];
    const float* wv = (const float*)d_in[3];
    const float* wo = (const float*)d_in[4];
    float* out = (float*)d_out;

    char* w = (char*)d_ws;
    unsigned short* xh  = (unsigned short*)(w);
    unsigned short* zh  = (unsigned short*)(w);
    unsigned short* qk  = (unsigned short*)(w + 33554432);
    unsigned short* vT  = (unsigned short*)(w + 50331648);
    unsigned short* wcatT = (unsigned short*)(w + 58720256);
    unsigned short* woT = (unsigned short*)(w + 65011712);
    float*          wcat = (float*)(w + 67108864);

    k_pack<<<dim3((DMODEL * QKV + 255) / 256), 256, 0, stream>>>(wq, wk, wv, wcat);
    k_transconv_h<<<dim3(32, 24), 256, 0, stream>>>(wcat, wcatT, DMODEL, QKV);
    k_transconv_h<<<dim3(8, 32), 256, 0, stream>>>(wo, woT, KVDIM, DMODEL);
    k_convh<<<dim3(16384), 256, 0, stream>>>(x, xh, MROWS * DMODEL / 4);
    k_gemm_qkv<<<dim3(64, 12), 256, 0, stream>>>(xh, wcatT, qk, vT);
    k_attn_mfma<<<dim3(16, NKV, BATCH), 256, 0, stream>>>(qk, vT, zh);
    k_gemm_out<<<dim3(64, 16), 256, 0, stream>>>(zh, woT, out);
}

// Round 12
// 201.427 us; speedup vs baseline: 2.7945x; 1.0705x over previous
//
#include <hip/hip_runtime.h>

typedef __attribute__((ext_vector_type(8))) _Float16 half8;
typedef __attribute__((ext_vector_type(4))) float f32x4;

#define BATCH  4
#define SLEN   2048
#define DMODEL 2048
#define NKV    8
#define GRP    4
#define DH     64
#define QKV    1536
#define KVDIM  512
#define MROWS  (BATCH * SLEN)   // 8192

// ---- fp16 helper (RNE via hardware cvt) ------------------------------------
__device__ __forceinline__ unsigned short f2h(float f) {
    union { _Float16 h; unsigned short u; } cv;
    cv.h = (_Float16)f;
    return cv.u;
}

// ---- async global->LDS, 16B per lane ---------------------------------------
__device__ __forceinline__ void gl16(const void* g, void* l) {
    __builtin_amdgcn_global_load_lds(
        (const __attribute__((address_space(1))) void*)g,
        (__attribute__((address_space(3))) void*)l, 16, 0, 0);
}

typedef __attribute__((ext_vector_type(4))) short short4v;
union U64S4 { unsigned long long u; short4v s; };

// ---------------------------------------------------------------------------
// Kernel 1: pack weights into Wcat[d_model][1536] (fp32).
// ---------------------------------------------------------------------------
__global__ __launch_bounds__(256) void k_pack(const float* __restrict__ wq,
                                              const float* __restrict__ wk,
                                              const float* __restrict__ wv,
                                              float* __restrict__ wcat) {
    int i = blockIdx.x * 256 + threadIdx.x;
    if (i >= DMODEL * QKV) return;
    int d = i / QKV, c = i - d * QKV;
    int mat = c >> 9, rem = c & 511;
    int n = rem >> 6, h = rem & 63;
    float val;
    if (mat == 0) {
        val = 0.0f;
#pragma unroll
        for (int g = 0; g < GRP; ++g)
            val += wq[((size_t)(n * GRP + g) * DMODEL + d) * DH + h];
    } else if (mat == 1) {
        val = wk[((size_t)n * DMODEL + d) * DH + h];
    } else {
        val = wv[((size_t)n * DMODEL + d) * DH + h];
    }
    wcat[(size_t)d * QKV + c] = val;
}

// ---------------------------------------------------------------------------
// Kernel 2: transpose + fp16 convert. in fp32 [R][C] -> fp16 ushort [C][R].
// ---------------------------------------------------------------------------
__global__ __launch_bounds__(256) void k_transconv_h(const float* __restrict__ in,
                                                     unsigned short* __restrict__ outT,
                                                     int R, int C) {
    __shared__ float T[64][65];
    const int r0 = blockIdx.x * 64, c0 = blockIdx.y * 64;
    const int tr = threadIdx.x >> 6, tc = threadIdx.x & 63;
#pragma unroll
    for (int i = 0; i < 16; ++i)
        T[tr + i * 4][tc] = in[(size_t)(r0 + tr + i * 4) * C + c0 + tc];
    __syncthreads();
    const int rr = tc;
#pragma unroll
    for (int i = 0; i < 16; ++i) {
        int cc = tr + i * 4;
        outT[(size_t)(c0 + cc) * R + r0 + rr] = f2h(T[rr][cc]);
    }
}

// ---------------------------------------------------------------------------
// Kernel 3: elementwise fp32 -> fp16.
// ---------------------------------------------------------------------------
__global__ __launch_bounds__(256) void k_convh(const float* __restrict__ in,
                                               unsigned short* __restrict__ out,
                                               int n4) {
    int i = blockIdx.x * 256 + threadIdx.x;
    if (i >= n4) return;
    float4 v = ((const float4*)in)[i];
    ushort4 o;
    o.x = f2h(v.x); o.y = f2h(v.y); o.z = f2h(v.z); o.w = f2h(v.w);
    ((ushort4*)out)[i] = o;
}

// ---------------------------------------------------------------------------
// Plain-fp16 2-phase MFMA GEMM (R5-proven structure) — unchanged from R8.
// ---------------------------------------------------------------------------
__device__ __forceinline__ void stage_tile64(const unsigned short* __restrict__ src,
                                             unsigned short* lds, int t, int K, int k0) {
#pragma unroll
    for (int j = 0; j < 4; ++j) {
        int slot = j * 256 + t;
        int row = slot >> 3, blk = slot & 7;
        int c = blk ^ (row & 7);
        gl16(src + (size_t)row * K + k0 + c * 8, lds + slot * 8);
    }
}

#define GEMMF16_MAIN(Ag, Bg, K_)                                              \
    const int t = threadIdx.x;                                                \
    const size_t m0 = (size_t)blockIdx.x * 128, n0 = (size_t)blockIdx.y * 128;\
    const int w = t >> 6, l = t & 63;                                         \
    const int wm = (w >> 1) * 64, wn = (w & 1) * 64;                          \
    const int r = l & 15, q = l >> 4;                                         \
    f32x4 acc[4][4] = {};                                                     \
    const int K = (K_);                                                       \
    const int NT = K / 64;                                                    \
    stage_tile64(Ag + m0 * K, A2[0], t, K, 0);                                \
    stage_tile64(Bg + n0 * K, B2[0], t, K, 0);                                \
    asm volatile("s_waitcnt vmcnt(0)" ::: "memory");                          \
    __builtin_amdgcn_s_barrier();                                             \
    int cur = 0;                                                              \
    for (int kt = 0; kt < NT; ++kt) {                                         \
        if (kt + 1 < NT) {                                                    \
            stage_tile64(Ag + m0 * K, A2[cur ^ 1], t, K, (kt + 1) * 64);      \
            stage_tile64(Bg + n0 * K, B2[cur ^ 1], t, K, (kt + 1) * 64);      \
        }                                                                     \
        const unsigned short* Ac = A2[cur];                                   \
        const unsigned short* Bc = B2[cur];                                   \
        half8 af[4][2], bf[4][2];                                             \
        _Pragma("unroll") for (int i = 0; i < 4; ++i)                         \
            _Pragma("unroll") for (int ks = 0; ks < 2; ++ks) {                \
                int ra = wm + i * 16 + r;                                     \
                af[i][ks] = *(const half8*)&Ac[ra * 64 +                      \
                    ((((ks << 2) | q) ^ (ra & 7)) << 3)];                     \
                int rb = wn + i * 16 + r;                                     \
                bf[i][ks] = *(const half8*)&Bc[rb * 64 +                      \
                    ((((ks << 2) | q) ^ (rb & 7)) << 3)];                     \
            }                                                                 \
        __builtin_amdgcn_s_setprio(1);                                        \
        _Pragma("unroll") for (int i = 0; i < 4; ++i)                         \
            _Pragma("unroll") for (int j = 0; j < 4; ++j) {                   \
                acc[i][j] = __builtin_amdgcn_mfma_f32_16x16x32_f16(           \
                    af[i][0], bf[j][0], acc[i][j], 0, 0, 0);                  \
                acc[i][j] = __builtin_amdgcn_mfma_f32_16x16x32_f16(           \
                    af[i][1], bf[j][1], acc[i][j], 0, 0, 0);                  \
            }                                                                 \
        __builtin_amdgcn_s_setprio(0);                                        \
        asm volatile("s_waitcnt vmcnt(0)" ::: "memory");                      \
        __builtin_amdgcn_s_barrier();                                         \
        cur ^= 1;                                                             \
    }

// ---------------------------------------------------------------------------
// Kernel 4: fp16 GEMM -> QKV (unchanged from R8).
// ---------------------------------------------------------------------------
__global__ __launch_bounds__(256) void k_gemm_qkv(
        const unsigned short* __restrict__ Ag, const unsigned short* __restrict__ Bg,
        unsigned short* __restrict__ qk, unsigned short* __restrict__ vT) {
    __shared__ unsigned short A2[2][128 * 64];
    __shared__ unsigned short B2[2][128 * 64];

    GEMMF16_MAIN(Ag, Bg, DMODEL)

    if (n0 < 1024) {
#pragma unroll
        for (int i = 0; i < 4; ++i)
#pragma unroll
            for (int j = 0; j < 4; ++j) {
                int col = (int)n0 + wn + j * 16 + r;
                size_t rowb = m0 + wm + i * 16 + q * 4;
#pragma unroll
                for (int e = 0; e < 4; ++e)
                    qk[(rowb + e) * 1024 + col] = f2h(acc[i][j][e]);
            }
    } else {
#pragma unroll
        for (int i = 0; i < 4; ++i)
#pragma unroll
            for (int j = 0; j < 4; ++j) {
                int d = (int)n0 - 1024 + wn + j * 16 + r;
                size_t rowb = m0 + wm + i * 16 + q * 4;
                ushort4 pk;
                pk.x = f2h(acc[i][j][0]); pk.y = f2h(acc[i][j][1]);
                pk.z = f2h(acc[i][j][2]); pk.w = f2h(acc[i][j][3]);
                *(ushort4*)&vT[(size_t)d * MROWS + rowb] = pk;
            }
    }
}

// ---------------------------------------------------------------------------
// Kernel 6: fp16 GEMM, fp32 C (output projection) — unchanged from R8.
// ---------------------------------------------------------------------------
__global__ __launch_bounds__(256) void k_gemm_out(
        const unsigned short* __restrict__ Ag, const unsigned short* __restrict__ Bg,
        float* __restrict__ C) {
    __shared__ unsigned short A2[2][128 * 64];
    __shared__ unsigned short B2[2][128 * 64];

    GEMMF16_MAIN(Ag, Bg, KVDIM)

#pragma unroll
    for (int i = 0; i < 4; ++i)
#pragma unroll
        for (int j = 0; j < 4; ++j) {
            int col = (int)n0 + wn + j * 16 + r;
            size_t rowb = m0 + wm + i * 16 + q * 4;
#pragma unroll
            for (int e = 0; e < 4; ++e)
                C[(rowb + e) * DMODEL + col] = acc[i][j][e];
        }
}

// ---------------------------------------------------------------------------
// Kernel 5: fp16 MFMA flash attention.  KVBLK=128 (R11, re-bench after
// infra failure).  Halves per-unit-work fixed costs (barrier, vmcnt drain,
// shuffle-reduce chains, alpha broadcast, Pt drains) that dominated at
// KVBLK=64 (R10: 1490 cyc/tile vs 77 cyc MFMA, MfmaUtil 8.5%).
//  - pairing stays uniform: kv-tiles per q-pair = 17 for every p.
//  - Ks [128 kv][64 d] rows 128B, swizzle blk^=(row&7) (unchanged).
//  - Vs [64 d][128 kv] rows 256B = 16 blocks, swizzle blk^=(d&15)
//    (bank check: 2-way, free).
//  - Pt per-wave 16q x 128kv (4KB); same per-32kv-chunk permutation,
//    chunk index kv>>5 now 0..3; tr_read path unchanged.
//  - last-tile causal mask elementwise vs global kv/q indices.
// LDS: Ks 32KB + Vs 32KB + Pt 16KB = 80KB -> 2 blocks/CU.
// ---------------------------------------------------------------------------
__global__ __launch_bounds__(256) void k_attn_mfma(
        const unsigned short* __restrict__ qk, const unsigned short* __restrict__ vT,
        unsigned short* __restrict__ zh) {
    __shared__ unsigned short Ks[2][128 * 64];
    __shared__ unsigned short Vs[2][64 * 128];
    __shared__ unsigned short Pt[4 * 128 * 16];   // per-wave 4KB

    const int t  = threadIdx.x;
    const int w  = t >> 6, l = t & 63;
    const int p  = blockIdx.x;        // 0..15 (pair index)
    const int n  = blockIdx.y, b = blockIdx.z;
    const int r  = l & 15, g = l >> 4;
    const int wq0 = w * 16;

    // staging: 4 K-slots + 4 V-slots per thread; dest linear, src inverse-swz
#define STAGE_KV(buf, kr0)                                                    \
    _Pragma("unroll") for (int j2 = 0; j2 < 4; ++j2) {                        \
        int s2 = j2 * 256 + t;                                                \
        int rK = s2 >> 3, cK = (s2 & 7) ^ (rK & 7);                           \
        gl16(qk + ((kr0) + rK) * 1024 + 512 + n * 64 + cK * 8,                \
             &Ks[buf][s2 * 8]);                                               \
        int rV = s2 >> 4, cV = (s2 & 15) ^ (rV & 15);                         \
        gl16(vT + (size_t)(n * 64 + rV) * MROWS + (kr0) + cV * 8,             \
             &Vs[buf][s2 * 8]);                                               \
    }

#pragma unroll 1
    for (int seg = 0; seg < 2; ++seg) {
        const int qt = seg ? p : (31 - p);   // heavy tile first
        const int nkt = (qt + 2) >> 1;       // ceil((qt+1)/2) kv-tiles of 128
        const size_t qrow0 = (size_t)(b * SLEN + qt * 64);

        // Q fragments, pre-scaled by 0.125 (exact power of two in fp16)
        half8 qh[2];
#pragma unroll
        for (int ks = 0; ks < 2; ++ks) {
            size_t off = (qrow0 + wq0 + r) * 1024 + n * 64 + ks * 32 + g * 8;
            qh[ks] = *(const half8*)(qk + off);
#pragma unroll
            for (int e2 = 0; e2 < 8; ++e2) qh[ks][e2] = qh[ks][e2] * (_Float16)0.125f;
        }

        STAGE_KV(0, (size_t)(b * SLEN))
        asm volatile("s_waitcnt vmcnt(0)" ::: "memory");
        __builtin_amdgcn_s_barrier();

        float m_[4], lsum[4];
#pragma unroll
        for (int e = 0; e < 4; ++e) { m_[e] = -3.0e38f; lsum[e] = 0.0f; }
        f32x4 accz[4] = {};

        for (int kt = 0; kt < nkt; ++kt) {
            const int cur = kt & 1;
            if (kt + 1 < nkt) {
                STAGE_KV(cur ^ 1, (size_t)(b * SLEN + (kt + 1) * 128))
            }
            const unsigned short* Ksc = Ks[cur];
            const unsigned short* Vsc = Vs[cur];

            // S = (Q/8).K^T over 128 kv (8 column-tiles of 16)
            f32x4 s[8] = {};
#pragma unroll
            for (int ct = 0; ct < 8; ++ct)
#pragma unroll
                for (int ks = 0; ks < 2; ++ks) {
                    int row = ct * 16 + r;
                    int off = row * 128 + (((ks * 4 + g) ^ (row & 7)) << 4);
                    half8 kh8 = *(const half8*)((char*)Ksc + off);
                    s[ct] = __builtin_amdgcn_mfma_f32_16x16x32_f16(qh[ks], kh8, s[ct], 0, 0, 0);
                }

            // causal mask: only the last kv-tile (wave-uniform branch)
            if (kt == nkt - 1) {
#pragma unroll
                for (int ct = 0; ct < 8; ++ct)
#pragma unroll
                    for (int e = 0; e < 4; ++e)
                        if ((kt * 128 + ct * 16 + r) > (qt * 64 + wq0 + g * 4 + e))
                            s[ct][e] = -100000.0f;   // reference IGNORE
            }

            // online softmax: row max + rescale (rows wq0+g*4+e on r-group)
            float al[4], nm[4];
#pragma unroll
            for (int e = 0; e < 4; ++e) {
                float pm = fmaxf(fmaxf(fmaxf(s[0][e], s[1][e]), fmaxf(s[2][e], s[3][e])),
                                 fmaxf(fmaxf(s[4][e], s[5][e]), fmaxf(s[6][e], s[7][e])));
                pm = fmaxf(pm, __shfl_xor(pm, 1));
                pm = fmaxf(pm, __shfl_xor(pm, 2));
                pm = fmaxf(pm, __shfl_xor(pm, 4));
                pm = fmaxf(pm, __shfl_xor(pm, 8));
                nm[e] = fmaxf(m_[e], pm);
                al[e] = __expf(m_[e] - nm[e]);
                m_[e] = nm[e];
            }
            {
                int src = (r >> 2) << 4;
                float a0 = __shfl(al[0], src), a1 = __shfl(al[1], src);
                float a2 = __shfl(al[2], src), a3 = __shfl(al[3], src);
                float ax = (r & 1) ? a1 : a0, ay = (r & 1) ? a3 : a2;
                float aq = (r & 2) ? ay : ax;
#pragma unroll
                for (int dt = 0; dt < 4; ++dt) {
                    accz[dt][0] *= aq; accz[dt][1] *= aq;
                    accz[dt][2] *= aq; accz[dt][3] *= aq;
                }
            }

            // P = exp(S - m), pack fp16, write P^T (row-permuted) to LDS
            float ps[4] = {};
#pragma unroll
            for (int ct = 0; ct < 8; ++ct) {
                float p0 = __expf(s[ct][0] - m_[0]);
                float p1 = __expf(s[ct][1] - m_[1]);
                float p2 = __expf(s[ct][2] - m_[2]);
                float p3 = __expf(s[ct][3] - m_[3]);
                ps[0] += p0; ps[1] += p1; ps[2] += p2; ps[3] += p3;
                short4v pk = { (short)f2h(p0), (short)f2h(p1),
                               (short)f2h(p2), (short)f2h(p3) };
                int kv = ct * 16 + r;
                int phys = (kv >> 5) * 32 + (((kv >> 2) & 1) << 4)
                         + (((kv >> 3) & 3) << 2) + (kv & 3);
                *(short4v*)((char*)Pt + w * 4096 + phys * 32 + g * 8) = pk;
            }

#pragma unroll
            for (int e = 0; e < 4; ++e) {
                float rs = ps[e];
                rs += __shfl_xor(rs, 1); rs += __shfl_xor(rs, 2);
                rs += __shfl_xor(rs, 4); rs += __shfl_xor(rs, 8);
                lsum[e] = lsum[e] * al[e] + rs;
            }

            // PV: z^T += V^T . P^T  (4 kv-chunks of 32; wave-private Pt)
            asm volatile("s_waitcnt lgkmcnt(0)" ::: "memory");
            __builtin_amdgcn_sched_barrier(0);
#pragma unroll
            for (int ks = 0; ks < 4; ++ks) {
                unsigned base = (unsigned)(size_t)((char*)Pt + w * 4096 + ks * 1024) + l * 8;
                U64S4 t1, t2;
                asm volatile("ds_read_b64_tr_b16 %0, %1" : "=v"(t1.u) : "v"(base) : "memory");
                asm volatile("ds_read_b64_tr_b16 %0, %1" : "=v"(t2.u) : "v"(base + 512) : "memory");
                asm volatile("s_waitcnt lgkmcnt(0)" ::: "memory");
                __builtin_amdgcn_sched_barrier(0);
                short4v pa = t1.s, pb = t2.s;
                union { short s[8]; half8 h; } pf;
                pf.s[0] = pa[0]; pf.s[1] = pa[1]; pf.s[2] = pa[2]; pf.s[3] = pa[3];
                pf.s[4] = pb[0]; pf.s[5] = pb[1]; pf.s[6] = pb[2]; pf.s[7] = pb[3];
#pragma unroll
                for (int dt = 0; dt < 4; ++dt) {
                    int d = dt * 16 + r;
                    int off = d * 256 + (((ks * 4 + g) ^ (d & 15)) << 4);
                    half8 vfrag = *(const half8*)((char*)Vsc + off);
                    accz[dt] = __builtin_amdgcn_mfma_f32_16x16x32_f16(vfrag, pf.h, accz[dt], 0, 0, 0);
                }
            }

            asm volatile("s_waitcnt vmcnt(0)" ::: "memory");   // next tile staged
            __builtin_amdgcn_s_barrier();
        }

        // normalize (1/l for this lane's accumulator column q=r), write z
        int src = (r >> 2) << 4;
        float l0 = __shfl(lsum[0], src), l1 = __shfl(lsum[1], src);
        float l2 = __shfl(lsum[2], src), l3 = __shfl(lsum[3], src);
        float lx = (r & 1) ? l1 : l0, ly = (r & 1) ? l3 : l2;
        float inv = 1.0f / ((r & 2) ? ly : lx);
#pragma unroll
        for (int dt = 0; dt < 4; ++dt) {
            ushort4 h4;
#pragma unroll
            for (int e = 0; e < 4; ++e)
                ((unsigned short*)&h4)[e] = f2h(accz[dt][e] * inv);
            size_t off = (qrow0 + wq0 + r) * 512 + n * 64 + dt * 16 + g * 4;
            *(ushort4*)(zh + off) = h4;
        }
    }
#undef STAGE_KV
}

// ---------------------------------------------------------------------------
// Workspace (bytes, 76 MB total):
//   0   : xh fp16 32M   -> after gemm1: zh fp16 8M (at 0)
//   32M : qk fp16 16M
//   48M : vT fp16 8M
//   56M : wcatT fp16 6M
//   62M : woT fp16 2M
//   64M : wcat fp32 12M (temp, dead after transconv)
// ---------------------------------------------------------------------------
extern "C" void kernel_launch(void* const* d_in, const int* in_sizes, int n_in,
                              void* d_out, int out_size, void* d_ws, size_t ws_size,
                              hipStream_t stream) {
    const float* x  = (const float*)d_in[0];
    const float* wq = (const float*)d_in[1];
    const float* wk = (const float*)d_in[2];
    const float* wv = (const float*)d_in[3];
    const float* wo = (const float*)d_in[4];
    float* out = (float*)d_out;

    char* w = (char*)d_ws;
    unsigned short* xh  = (unsigned short*)(w);
    unsigned short* zh  = (unsigned short*)(w);
    unsigned short* qk  = (unsigned short*)(w + 33554432);
    unsigned short* vT  = (unsigned short*)(w + 50331648);
    unsigned short* wcatT = (unsigned short*)(w + 58720256);
    unsigned short* woT = (unsigned short*)(w + 65011712);
    float*          wcat = (float*)(w + 67108864);

    k_pack<<<dim3((DMODEL * QKV + 255) / 256), 256, 0, stream>>>(wq, wk, wv, wcat);
    k_transconv_h<<<dim3(32, 24), 256, 0, stream>>>(wcat, wcatT, DMODEL, QKV);
    k_transconv_h<<<dim3(8, 32), 256, 0, stream>>>(wo, woT, KVDIM, DMODEL);
    k_convh<<<dim3(16384), 256, 0, stream>>>(x, xh, MROWS * DMODEL / 4);
    k_gemm_qkv<<<dim3(64, 12), 256, 0, stream>>>(xh, wcatT, qk, vT);
    k_attn_mfma<<<dim3(16, NKV, BATCH), 256, 0, stream>>>(qk, vT, zh);
    k_gemm_out<<<dim3(64, 16), 256, 0, stream>>>(zh, woT, out);
}

// Round 16
// 187.753 us; speedup vs baseline: 2.9980x; 1.0728x over previous
//
#include <hip/hip_runtime.h>

typedef __attribute__((ext_vector_type(8))) _Float16 half8;
typedef __attribute__((ext_vector_type(4))) float f32x4;

#define BATCH  4
#define SLEN   2048
#define DMODEL 2048
#define NKV    8
#define GRP    4
#define DH     64
#define QKV    1536
#define KVDIM  512
#define MROWS  (BATCH * SLEN)   // 8192

// ---- fp16 helper (RNE via hardware cvt) ------------------------------------
__device__ __forceinline__ unsigned short f2h(float f) {
    union { _Float16 h; unsigned short u; } cv;
    cv.h = (_Float16)f;
    return cv.u;
}

// ---- async global->LDS, 16B per lane ---------------------------------------
__device__ __forceinline__ void gl16(const void* g, void* l) {
    __builtin_amdgcn_global_load_lds(
        (const __attribute__((address_space(1))) void*)g,
        (__attribute__((address_space(3))) void*)l, 16, 0, 0);
}

typedef __attribute__((ext_vector_type(4))) short short4v;
union U64S4 { unsigned long long u; short4v s; };

// ---------------------------------------------------------------------------
// Kernel 1 (fused pack + transpose + fp16): wcatT[c][d], c = mat*512+n*64+h.
// mat 0: sum_g W_Q[n*4+g] (reference sums g in the scores einsum); 1: W_K;
// 2: W_V.  64x64 LDS tile: coalesced reads (h contiguous) and writes
// (d contiguous).  Replaces k_pack + first k_transconv_h (saves the 12MB
// fp32 intermediate round-trip and one launch).
// ---------------------------------------------------------------------------
__global__ __launch_bounds__(256) void k_packT(const float* __restrict__ wq,
                                               const float* __restrict__ wk,
                                               const float* __restrict__ wv,
                                               unsigned short* __restrict__ outT) {
    __shared__ float T[64][65];
    const int d0 = blockIdx.x * 64;          // d-tile (32)
    const int ct = blockIdx.y;               // 0..23
    const int mat = ct >> 3, n = ct & 7;
    const int tr = threadIdx.x >> 6, tc = threadIdx.x & 63;
#pragma unroll
    for (int i = 0; i < 16; ++i) {
        int row = tr + i * 4;                // d-local
        float v;
        if (mat == 0) {
            v = 0.0f;
#pragma unroll
            for (int g = 0; g < GRP; ++g)
                v += wq[((size_t)(n * GRP + g) * DMODEL + d0 + row) * DH + tc];
        } else if (mat == 1) {
            v = wk[((size_t)n * DMODEL + d0 + row) * DH + tc];
        } else {
            v = wv[((size_t)n * DMODEL + d0 + row) * DH + tc];
        }
        T[row][tc] = v;
    }
    __syncthreads();
    const int rr = tc;                       // d-local
#pragma unroll
    for (int i = 0; i < 16; ++i) {
        int cc = tr + i * 4;                 // h-local
        outT[(size_t)(mat * 512 + n * 64 + cc) * DMODEL + d0 + rr] = f2h(T[rr][cc]);
    }
}

// ---------------------------------------------------------------------------
// Kernel 2: transpose + fp16 convert (still used for W_O).
// ---------------------------------------------------------------------------
__global__ __launch_bounds__(256) void k_transconv_h(const float* __restrict__ in,
                                                     unsigned short* __restrict__ outT,
                                                     int R, int C) {
    __shared__ float T[64][65];
    const int r0 = blockIdx.x * 64, c0 = blockIdx.y * 64;
    const int tr = threadIdx.x >> 6, tc = threadIdx.x & 63;
#pragma unroll
    for (int i = 0; i < 16; ++i)
        T[tr + i * 4][tc] = in[(size_t)(r0 + tr + i * 4) * C + c0 + tc];
    __syncthreads();
    const int rr = tc;
#pragma unroll
    for (int i = 0; i < 16; ++i) {
        int cc = tr + i * 4;
        outT[(size_t)(c0 + cc) * R + r0 + rr] = f2h(T[rr][cc]);
    }
}

// ---------------------------------------------------------------------------
// Kernel 3: elementwise fp32 -> fp16.
// ---------------------------------------------------------------------------
__global__ __launch_bounds__(256) void k_convh(const float* __restrict__ in,
                                               unsigned short* __restrict__ out,
                                               int n4) {
    int i = blockIdx.x * 256 + threadIdx.x;
    if (i >= n4) return;
    float4 v = ((const float4*)in)[i];
    ushort4 o;
    o.x = f2h(v.x); o.y = f2h(v.y); o.z = f2h(v.z); o.w = f2h(v.w);
    ((ushort4*)out)[i] = o;
}

// ---------------------------------------------------------------------------
// fp16 2-phase MFMA GEMM staging (R5-proven swizzle: dest linear,
// source inverse-swizzled, ds_read compensates -> 0 bank conflicts).
// ---------------------------------------------------------------------------
__device__ __forceinline__ void stage_rows(const unsigned short* __restrict__ src,
                                           unsigned short* lds, int t, int K,
                                           int k0, int nslots4) {
#pragma unroll
    for (int j = 0; j < 8; ++j) {
        if (j >= nslots4) break;
        int slot = j * 256 + t;
        int row = slot >> 3, blk = slot & 7;
        int c = blk ^ (row & 7);
        gl16(src + (size_t)row * K + k0 + c * 8, lds + slot * 8);
    }
}

// ---------------------------------------------------------------------------
// Kernel 4: fp16 GEMM -> QKV.  Tile 128x192 -> grid 64x8 = 512 blocks
// = exactly one resident wave at 2 blocks/CU (removes the 768-block tail
// that idled ~25% of the kernel at the 128x128 tiling).
// Per K-step per wave: 48 MFMA, 20 ds_read_b128 (ratio 2.4 vs 2.0).
// LDS: A 2x16KB + B 2x24KB = 80KB -> 2 blocks/CU.
// ---------------------------------------------------------------------------
__global__ __launch_bounds__(256) void k_gemm_qkv(
        const unsigned short* __restrict__ Ag, const unsigned short* __restrict__ Bg,
        unsigned short* __restrict__ qk, unsigned short* __restrict__ vT) {
    __shared__ unsigned short A2[2][128 * 64];
    __shared__ unsigned short B2[2][192 * 64];

    const int t = threadIdx.x;
    const size_t m0 = (size_t)blockIdx.x * 128, n0 = (size_t)blockIdx.y * 192;
    const int w = t >> 6, l = t & 63;
    const int wm = (w >> 1) * 64, wn = (w & 1) * 96;
    const int r = l & 15, q = l >> 4;
    f32x4 acc[4][6] = {};
    const int K = DMODEL;
    const int NT = K / 64;

    stage_rows(Ag + m0 * K, A2[0], t, K, 0, 4);
    stage_rows(Bg + n0 * K, B2[0], t, K, 0, 6);
    asm volatile("s_waitcnt vmcnt(0)" ::: "memory");
    __builtin_amdgcn_s_barrier();
    int cur = 0;
    for (int kt = 0; kt < NT; ++kt) {
        if (kt + 1 < NT) {
            stage_rows(Ag + m0 * K, A2[cur ^ 1], t, K, (kt + 1) * 64, 4);
            stage_rows(Bg + n0 * K, B2[cur ^ 1], t, K, (kt + 1) * 64, 6);
        }
        const unsigned short* Ac = A2[cur];
        const unsigned short* Bc = B2[cur];
        half8 af[4][2], bf[6][2];
#pragma unroll
        for (int i = 0; i < 4; ++i)
#pragma unroll
            for (int ks = 0; ks < 2; ++ks) {
                int ra = wm + i * 16 + r;
                af[i][ks] = *(const half8*)&Ac[ra * 64 + ((((ks << 2) | q) ^ (ra & 7)) << 3)];
            }
#pragma unroll
        for (int j = 0; j < 6; ++j)
#pragma unroll
            for (int ks = 0; ks < 2; ++ks) {
                int rb = wn + j * 16 + r;
                bf[j][ks] = *(const half8*)&Bc[rb * 64 + ((((ks << 2) | q) ^ (rb & 7)) << 3)];
            }
        __builtin_amdgcn_s_setprio(1);
#pragma unroll
        for (int i = 0; i < 4; ++i)
#pragma unroll
            for (int j = 0; j < 6; ++j) {
                acc[i][j] = __builtin_amdgcn_mfma_f32_16x16x32_f16(af[i][0], bf[j][0], acc[i][j], 0, 0, 0);
                acc[i][j] = __builtin_amdgcn_mfma_f32_16x16x32_f16(af[i][1], bf[j][1], acc[i][j], 0, 0, 0);
            }
        __builtin_amdgcn_s_setprio(0);
        asm volatile("s_waitcnt vmcnt(0)" ::: "memory");
        __builtin_amdgcn_s_barrier();
        cur ^= 1;
    }

    // epilogue: per-(i,j) Q/K vs V branch (col boundary 1024 is 16-aligned)
#pragma unroll
    for (int i = 0; i < 4; ++i)
#pragma unroll
        for (int j = 0; j < 6; ++j) {
            int col = (int)n0 + wn + j * 16 + r;
            size_t rowb = m0 + wm + i * 16 + q * 4;
            if (col < 1024) {
#pragma unroll
                for (int e = 0; e < 4; ++e)
                    qk[(rowb + e) * 1024 + col] = f2h(acc[i][j][e]);
            } else {
                int d = col - 1024;
                ushort4 pk;
                pk.x = f2h(acc[i][j][0]); pk.y = f2h(acc[i][j][1]);
                pk.z = f2h(acc[i][j][2]); pk.w = f2h(acc[i][j][3]);
                *(ushort4*)&vT[(size_t)d * MROWS + rowb] = pk;
            }
        }
}

// ---------------------------------------------------------------------------
// Kernel 6: fp16 GEMM 128x128, fp32 C (output projection).
// Grid 64x16 = 1024 blocks = exactly 2 resident waves.
// ---------------------------------------------------------------------------
__global__ __launch_bounds__(256) void k_gemm_out(
        const unsigned short* __restrict__ Ag, const unsigned short* __restrict__ Bg,
        float* __restrict__ C) {
    __shared__ unsigned short A2[2][128 * 64];
    __shared__ unsigned short B2[2][128 * 64];

    const int t = threadIdx.x;
    const size_t m0 = (size_t)blockIdx.x * 128, n0 = (size_t)blockIdx.y * 128;
    const int w = t >> 6, l = t & 63;
    const int wm = (w >> 1) * 64, wn = (w & 1) * 64;
    const int r = l & 15, q = l >> 4;
    f32x4 acc[4][4] = {};
    const int K = KVDIM;
    const int NT = K / 64;

    stage_rows(Ag + m0 * K, A2[0], t, K, 0, 4);
    stage_rows(Bg + n0 * K, B2[0], t, K, 0, 4);
    asm volatile("s_waitcnt vmcnt(0)" ::: "memory");
    __builtin_amdgcn_s_barrier();
    int cur = 0;
    for (int kt = 0; kt < NT; ++kt) {
        if (kt + 1 < NT) {
            stage_rows(Ag + m0 * K, A2[cur ^ 1], t, K, (kt + 1) * 64, 4);
            stage_rows(Bg + n0 * K, B2[cur ^ 1], t, K, (kt + 1) * 64, 4);
        }
        const unsigned short* Ac = A2[cur];
        const unsigned short* Bc = B2[cur];
        half8 af[4][2], bf[4][2];
#pragma unroll
        for (int i = 0; i < 4; ++i)
#pragma unroll
            for (int ks = 0; ks < 2; ++ks) {
                int ra = wm + i * 16 + r;
                af[i][ks] = *(const half8*)&Ac[ra * 64 + ((((ks << 2) | q) ^ (ra & 7)) << 3)];
                int rb = wn + i * 16 + r;
                bf[i][ks] = *(const half8*)&Bc[rb * 64 + ((((ks << 2) | q) ^ (rb & 7)) << 3)];
            }
        __builtin_amdgcn_s_setprio(1);
#pragma unroll
        for (int i = 0; i < 4; ++i)
#pragma unroll
            for (int j = 0; j < 4; ++j) {
                acc[i][j] = __builtin_amdgcn_mfma_f32_16x16x32_f16(af[i][0], bf[j][0], acc[i][j], 0, 0, 0);
                acc[i][j] = __builtin_amdgcn_mfma_f32_16x16x32_f16(af[i][1], bf[j][1], acc[i][j], 0, 0, 0);
            }
        __builtin_amdgcn_s_setprio(0);
        asm volatile("s_waitcnt vmcnt(0)" ::: "memory");
        __builtin_amdgcn_s_barrier();
        cur ^= 1;
    }

#pragma unroll
    for (int i = 0; i < 4; ++i)
#pragma unroll
        for (int j = 0; j < 4; ++j) {
            int col = (int)n0 + wn + j * 16 + r;
            size_t rowb = m0 + wm + i * 16 + q * 4;
#pragma unroll
            for (int e = 0; e < 4; ++e)
                C[(rowb + e) * DMODEL + col] = acc[i][j][e];
        }
}

// ---------------------------------------------------------------------------
// Kernel 5: fp16 MFMA flash attention, KVBLK=128 (R12-verified, unchanged).
// ---------------------------------------------------------------------------
__global__ __launch_bounds__(256) void k_attn_mfma(
        const unsigned short* __restrict__ qk, const unsigned short* __restrict__ vT,
        unsigned short* __restrict__ zh) {
    __shared__ unsigned short Ks[2][128 * 64];
    __shared__ unsigned short Vs[2][64 * 128];
    __shared__ unsigned short Pt[4 * 128 * 16];   // per-wave 4KB

    const int t  = threadIdx.x;
    const int w  = t >> 6, l = t & 63;
    const int p  = blockIdx.x;        // 0..15 (pair index)
    const int n  = blockIdx.y, b = blockIdx.z;
    const int r  = l & 15, g = l >> 4;
    const int wq0 = w * 16;

#define STAGE_KV(buf, kr0)                                                    \
    _Pragma("unroll") for (int j2 = 0; j2 < 4; ++j2) {                        \
        int s2 = j2 * 256 + t;                                                \
        int rK = s2 >> 3, cK = (s2 & 7) ^ (rK & 7);                           \
        gl16(qk + ((kr0) + rK) * 1024 + 512 + n * 64 + cK * 8,                \
             &Ks[buf][s2 * 8]);                                               \
        int rV = s2 >> 4, cV = (s2 & 15) ^ (rV & 15);                         \
        gl16(vT + (size_t)(n * 64 + rV) * MROWS + (kr0) + cV * 8,             \
             &Vs[buf][s2 * 8]);                                               \
    }

#pragma unroll 1
    for (int seg = 0; seg < 2; ++seg) {
        const int qt = seg ? p : (31 - p);   // heavy tile first
        const int nkt = (qt + 2) >> 1;       // ceil((qt+1)/2) kv-tiles of 128
        const size_t qrow0 = (size_t)(b * SLEN + qt * 64);

        half8 qh[2];
#pragma unroll
        for (int ks = 0; ks < 2; ++ks) {
            size_t off = (qrow0 + wq0 + r) * 1024 + n * 64 + ks * 32 + g * 8;
            qh[ks] = *(const half8*)(qk + off);
#pragma unroll
            for (int e2 = 0; e2 < 8; ++e2) qh[ks][e2] = qh[ks][e2] * (_Float16)0.125f;
        }

        STAGE_KV(0, (size_t)(b * SLEN))
        asm volatile("s_waitcnt vmcnt(0)" ::: "memory");
        __builtin_amdgcn_s_barrier();

        float m_[4], lsum[4];
#pragma unroll
        for (int e = 0; e < 4; ++e) { m_[e] = -3.0e38f; lsum[e] = 0.0f; }
        f32x4 accz[4] = {};

        for (int kt = 0; kt < nkt; ++kt) {
            const int cur = kt & 1;
            if (kt + 1 < nkt) {
                STAGE_KV(cur ^ 1, (size_t)(b * SLEN + (kt + 1) * 128))
            }
            const unsigned short* Ksc = Ks[cur];
            const unsigned short* Vsc = Vs[cur];

            f32x4 s[8] = {};
#pragma unroll
            for (int ct = 0; ct < 8; ++ct)
#pragma unroll
                for (int ks = 0; ks < 2; ++ks) {
                    int row = ct * 16 + r;
                    int off = row * 128 + (((ks * 4 + g) ^ (row & 7)) << 4);
                    half8 kh8 = *(const half8*)((char*)Ksc + off);
                    s[ct] = __builtin_amdgcn_mfma_f32_16x16x32_f16(qh[ks], kh8, s[ct], 0, 0, 0);
                }

            if (kt == nkt - 1) {
#pragma unroll
                for (int ct = 0; ct < 8; ++ct)
#pragma unroll
                    for (int e = 0; e < 4; ++e)
                        if ((kt * 128 + ct * 16 + r) > (qt * 64 + wq0 + g * 4 + e))
                            s[ct][e] = -100000.0f;   // reference IGNORE
            }

            float al[4], nm[4];
#pragma unroll
            for (int e = 0; e < 4; ++e) {
                float pm = fmaxf(fmaxf(fmaxf(s[0][e], s[1][e]), fmaxf(s[2][e], s[3][e])),
                                 fmaxf(fmaxf(s[4][e], s[5][e]), fmaxf(s[6][e], s[7][e])));
                pm = fmaxf(pm, __shfl_xor(pm, 1));
                pm = fmaxf(pm, __shfl_xor(pm, 2));
                pm = fmaxf(pm, __shfl_xor(pm, 4));
                pm = fmaxf(pm, __shfl_xor(pm, 8));
                nm[e] = fmaxf(m_[e], pm);
                al[e] = __expf(m_[e] - nm[e]);
                m_[e] = nm[e];
            }
            {
                int src = (r >> 2) << 4;
                float a0 = __shfl(al[0], src), a1 = __shfl(al[1], src);
                float a2 = __shfl(al[2], src), a3 = __shfl(al[3], src);
                float ax = (r & 1) ? a1 : a0, ay = (r & 1) ? a3 : a2;
                float aq = (r & 2) ? ay : ax;
#pragma unroll
                for (int dt = 0; dt < 4; ++dt) {
                    accz[dt][0] *= aq; accz[dt][1] *= aq;
                    accz[dt][2] *= aq; accz[dt][3] *= aq;
                }
            }

            float ps[4] = {};
#pragma unroll
            for (int ct = 0; ct < 8; ++ct) {
                float p0 = __expf(s[ct][0] - m_[0]);
                float p1 = __expf(s[ct][1] - m_[1]);
                float p2 = __expf(s[ct][2] - m_[2]);
                float p3 = __expf(s[ct][3] - m_[3]);
                ps[0] += p0; ps[1] += p1; ps[2] += p2; ps[3] += p3;
                short4v pk = { (short)f2h(p0), (short)f2h(p1),
                               (short)f2h(p2), (short)f2h(p3) };
                int kv = ct * 16 + r;
                int phys = (kv >> 5) * 32 + (((kv >> 2) & 1) << 4)
                         + (((kv >> 3) & 3) << 2) + (kv & 3);
                *(short4v*)((char*)Pt + w * 4096 + phys * 32 + g * 8) = pk;
            }

#pragma unroll
            for (int e = 0; e < 4; ++e) {
                float rs = ps[e];
                rs += __shfl_xor(rs, 1); rs += __shfl_xor(rs, 2);
                rs += __shfl_xor(rs, 4); rs += __shfl_xor(rs, 8);
                lsum[e] = lsum[e] * al[e] + rs;
            }

            asm volatile("s_waitcnt lgkmcnt(0)" ::: "memory");
            __builtin_amdgcn_sched_barrier(0);
#pragma unroll
            for (int ks = 0; ks < 4; ++ks) {
                unsigned base = (unsigned)(size_t)((char*)Pt + w * 4096 + ks * 1024) + l * 8;
                U64S4 t1, t2;
                asm volatile("ds_read_b64_tr_b16 %0, %1" : "=v"(t1.u) : "v"(base) : "memory");
                asm volatile("ds_read_b64_tr_b16 %0, %1" : "=v"(t2.u) : "v"(base + 512) : "memory");
                asm volatile("s_waitcnt lgkmcnt(0)" ::: "memory");
                __builtin_amdgcn_sched_barrier(0);
                short4v pa = t1.s, pb = t2.s;
                union { short s[8]; half8 h; } pf;
                pf.s[0] = pa[0]; pf.s[1] = pa[1]; pf.s[2] = pa[2]; pf.s[3] = pa[3];
                pf.s[4] = pb[0]; pf.s[5] = pb[1]; pf.s[6] = pb[2]; pf.s[7] = pb[3];
#pragma unroll
                for (int dt = 0; dt < 4; ++dt) {
                    int d = dt * 16 + r;
                    int off = d * 256 + (((ks * 4 + g) ^ (d & 15)) << 4);
                    half8 vfrag = *(const half8*)((char*)Vsc + off);
                    accz[dt] = __builtin_amdgcn_mfma_f32_16x16x32_f16(vfrag, pf.h, accz[dt], 0, 0, 0);
                }
            }

            asm volatile("s_waitcnt vmcnt(0)" ::: "memory");   // next tile staged
            __builtin_amdgcn_s_barrier();
        }

        int src = (r >> 2) << 4;
        float l0 = __shfl(lsum[0], src), l1 = __shfl(lsum[1], src);
        float l2 = __shfl(lsum[2], src), l3 = __shfl(lsum[3], src);
        float lx = (r & 1) ? l1 : l0, ly = (r & 1) ? l3 : l2;
        float inv = 1.0f / ((r & 2) ? ly : lx);
#pragma unroll
        for (int dt = 0; dt < 4; ++dt) {
            ushort4 h4;
#pragma unroll
            for (int e = 0; e < 4; ++e)
                ((unsigned short*)&h4)[e] = f2h(accz[dt][e] * inv);
            size_t off = (qrow0 + wq0 + r) * 512 + n * 64 + dt * 16 + g * 4;
            *(ushort4*)(zh + off) = h4;
        }
    }
#undef STAGE_KV
}

// ---------------------------------------------------------------------------
// Workspace (bytes, 64 MB used):
//   0   : xh fp16 32M   -> after gemm1: zh fp16 8M (at 0)
//   32M : qk fp16 16M
//   48M : vT fp16 8M
//   56M : wcatT fp16 6M
//   62M : woT fp16 2M
// ---------------------------------------------------------------------------
extern "C" void kernel_launch(void* const* d_in, const int* in_sizes, int n_in,
                              void* d_out, int out_size, void* d_ws, size_t ws_size,
                              hipStream_t stream) {
    const float* x  = (const float*)d_in[0];
    const float* wq = (const float*)d_in[1];
    const float* wk = (const float*)d_in[2];
    const float* wv = (const float*)d_in[3];
    const float* wo = (const float*)d_in[4];
    float* out = (float*)d_out;

    char* w = (char*)d_ws;
    unsigned short* xh  = (unsigned short*)(w);
    unsigned short* zh  = (unsigned short*)(w);
    unsigned short* qk  = (unsigned short*)(w + 33554432);
    unsigned short* vT  = (unsigned short*)(w + 50331648);
    unsigned short* wcatT = (unsigned short*)(w + 58720256);
    unsigned short* woT = (unsigned short*)(w + 65011712);

    k_packT<<<dim3(32, 24), 256, 0, stream>>>(wq, wk, wv, wcatT);
    k_transconv_h<<<dim3(8, 32), 256, 0, stream>>>(wo, woT, KVDIM, DMODEL);
    k_convh<<<dim3(16384), 256, 0, stream>>>(x, xh, MROWS * DMODEL / 4);
    k_gemm_qkv<<<dim3(64, 8), 256, 0, stream>>>(xh, wcatT, qk, vT);
    k_attn_mfma<<<dim3(16, NKV, BATCH), 256, 0, stream>>>(qk, vT, zh);
    k_gemm_out<<<dim3(64, 16), 256, 0, stream>>>(zh, woT, out);
}